// Round 5
// baseline (229.082 us; speedup 1.0000x reference)
//
#include <hip/hip_runtime.h>
#include <math.h>
#include <float.h>
#include <limits.h>

// Problem constants
#define PIX    13824   // 64*216
#define QPIX   3456    // 32*108
#define QW     108
#define QH     32
#define NPTS   8192
#define MCAP   3072    // per-quadrant center capacity (expected ~2048, 26 sigma)
#define KT2    27      // QPIX/128 (k4a key tiles)
#define SPLITS 24      // center-range splits for k4a

typedef float vf2 __attribute__((ext_vector_type(2)));

// ---------------------------------------------------------------------------
// K1: feat/value linear maps + fold to [r][k][c] pixel-major + feat inv-norm.
// Also zeroes agg+denom+cnt (aggregation state) - no separate memset dispatch.
// ---------------------------------------------------------------------------
__global__ __launch_bounds__(256) void k1_linmaps(
    const float* __restrict__ x, const float* __restrict__ Wf, const float* __restrict__ bf,
    const float* __restrict__ Wv, const float* __restrict__ bv,
    float* __restrict__ featp, float* __restrict__ valp, float* __restrict__ invn,
    float* __restrict__ aggz)
{
    __shared__ float ssq[4][64];
    int t = threadIdx.x;

    // zero agg(786432) + denom(12288) + cnt(12288) = 811008 floats = 202752 float4
    {
        float4 z4 = make_float4(0.f, 0.f, 0.f, 0.f);
        for (int i = blockIdx.x * 256 + t; i < 202752; i += 216 * 256)
            ((float4*)aggz)[i] = z4;
    }

    int lane = t & 63;
    int q = t >> 6;                       // wave id -> o-group (wave-uniform)
    int pix = blockIdx.x * 64 + lane;     // 216*64 = 13824 exact
    int h = pix / 216;
    int w = pix - h * 216;
    int r = ((h >> 5) << 1) | (w >= QW ? 1 : 0);
    int k = (h & 31) * QW + (w >= QW ? w - QW : w);

    float xr[64];
    #pragma unroll
    for (int c = 0; c < 64; c++) xr[c] = x[c * PIX + pix];

    size_t base = ((size_t)(r * QPIX + k)) * 64 + q * 16;
    float ss = 0.0f;
    for (int i = 0; i < 16; i++) {
        int o = q * 16 + i;               // wave-uniform
        float af = bf[o], av = bv[o];
        #pragma unroll
        for (int c = 0; c < 64; c++) {
            af = fmaf(Wf[o * 64 + c], xr[c], af);
            av = fmaf(Wv[o * 64 + c], xr[c], av);
        }
        featp[base + i] = af;
        valp[base + i]  = av;
        ss += af * af;
    }
    ssq[q][lane] = ss;
    __syncthreads();
    if (q == 0) {
        float tot = ssq[0][lane] + ssq[1][lane] + ssq[2][lane] + ssq[3][lane];
        invn[r * QPIX + k] = 1.0f / fmaxf(sqrtf(tot), 1e-12f);
    }
}

// ---------------------------------------------------------------------------
// K2 (order-preserving compaction):
//   k2a: per-64-point-chunk quadrant counts (128 chunks)
//   k2c: per-block redundant scan of chunk counts + ranked scatter
// ---------------------------------------------------------------------------
__device__ __forceinline__ int point_quadrant(float px, float py) {
    // rh = 384/2 = 192 exact, rw = 1296/2 = 648 exact
    return ((py > 192.0f) ? 2 : 0) + ((px > 648.0f) ? 1 : 0);
}

__global__ __launch_bounds__(64) void k2a_count(
    const float* __restrict__ points, int* __restrict__ ccnt)
{
    int lane = threadIdx.x;
    int chunk = blockIdx.x;
    float2 p = ((const float2*)points)[chunk * 64 + lane];
    int q = point_quadrant(p.x, p.y);
    #pragma unroll
    for (int r = 0; r < 4; r++) {
        unsigned long long m = __ballot(q == r);
        if (lane == 0) ccnt[chunk * 4 + r] = __popcll(m);
    }
}

__global__ __launch_bounds__(64) void k2c_scatter(
    const float* __restrict__ points, const int* __restrict__ ccnt,
    float* __restrict__ cp, int* __restrict__ slot, int* __restrict__ counts)
{
    int lane = threadIdx.x;
    int chunk = blockIdx.x;

    // redundant per-block scan: prefix over chunks < my chunk, per quadrant
    int c0[4], c1[4], pre[4];
    #pragma unroll
    for (int r = 0; r < 4; r++) {
        c0[r] = ccnt[lane * 4 + r];
        c1[r] = ccnt[(lane + 64) * 4 + r];
        pre[r] = (lane < chunk ? c0[r] : 0) + (lane + 64 < chunk ? c1[r] : 0);
    }
    #pragma unroll
    for (int d = 1; d < 64; d <<= 1) {
        #pragma unroll
        for (int r = 0; r < 4; r++) pre[r] += __shfl_xor(pre[r], d, 64);
    }
    if (chunk == 0) {   // block 0 also publishes the totals
        int full[4];
        #pragma unroll
        for (int r = 0; r < 4; r++) full[r] = c0[r] + c1[r];
        #pragma unroll
        for (int d = 1; d < 64; d <<= 1) {
            #pragma unroll
            for (int r = 0; r < 4; r++) full[r] += __shfl_xor(full[r], d, 64);
        }
        if (lane == 0) {
            #pragma unroll
            for (int r = 0; r < 4; r++) counts[r] = full[r];
        }
    }

    int n = chunk * 64 + lane;
    float2 p = ((const float2*)points)[n];
    int q = point_quadrant(p.x, p.y);
    unsigned long long below = (lane == 0) ? 0ull : (~0ull >> (64 - lane));
    #pragma unroll
    for (int r = 0; r < 4; r++) {
        unsigned long long m = __ballot(q == r);
        if (q == r) {
            int pos = pre[r] + __popcll(m & below);
            ((float2*)cp)[r * MCAP + pos] = p;
            slot[n] = r * MCAP + pos;
        }
    }
}

// ---------------------------------------------------------------------------
// K3: bilinear gather (border clamp) of feat & value at compacted points;
// slot m == K_r is the phantom (0,0) padded row. 4 channel-groups per point
// (256-thread blocks, 16 ch/thread).
// ---------------------------------------------------------------------------
__global__ __launch_bounds__(256) void k3_gather(
    const float* __restrict__ featp, const float* __restrict__ valp,
    const float* __restrict__ cp, const int* __restrict__ counts,
    float* __restrict__ cn, float* __restrict__ vc)
{
    __shared__ float ssq[64][5];
    int r = blockIdx.y;
    int t = threadIdx.x;
    int g = t & 3, p = t >> 2;          // g: channel group, p: point in tile
    int m = blockIdx.x * 64 + p;
    int K = counts[r];
    int Mr = min(K + 1, MCAP);
    bool active = m < Mr;

    float px = 0.0f, py = 0.0f;
    if (m < K) { float2 pt = ((const float2*)cp)[r * MCAP + m]; px = pt.x; py = pt.y; }

    // mirror reference op order: grid = p/(S-1)*2-1 ; g = (grid+1)*(D/2)-0.5
    float gx = (px / 1295.0f * 2.0f - 1.0f + 1.0f) * 54.0f - 0.5f;
    float gy = (py / 383.0f  * 2.0f - 1.0f + 1.0f) * 16.0f - 0.5f;
    float x0 = floorf(gx), y0 = floorf(gy);
    float wx = gx - x0, wy = gy - y0;
    int x0i = (int)fminf(fmaxf(x0,         0.0f), 107.0f);
    int x1i = (int)fminf(fmaxf(x0 + 1.0f,  0.0f), 107.0f);
    int y0i = (int)fminf(fmaxf(y0,         0.0f), 31.0f);
    int y1i = (int)fminf(fmaxf(y0 + 1.0f,  0.0f), 31.0f);
    float w00 = (1.0f - wx) * (1.0f - wy);
    float w01 = wx * (1.0f - wy);
    float w10 = (1.0f - wx) * wy;
    float w11 = wx * wy;

    int c0 = g * 16;
    size_t b00 = ((size_t)(r * QPIX + y0i * QW + x0i)) * 64 + c0;
    size_t b01 = ((size_t)(r * QPIX + y0i * QW + x1i)) * 64 + c0;
    size_t b10 = ((size_t)(r * QPIX + y1i * QW + x0i)) * 64 + c0;
    size_t b11 = ((size_t)(r * QPIX + y1i * QW + x1i)) * 64 + c0;
    size_t ob  = ((size_t)(r * MCAP + m)) * 64 + c0;

    float fr[16];
    float ss = 0.0f;
    #pragma unroll
    for (int c = 0; c < 16; c += 4) {
        float4 a  = *(const float4*)(featp + b00 + c);
        float4 b_ = *(const float4*)(featp + b01 + c);
        float4 gg = *(const float4*)(featp + b10 + c);
        float4 d  = *(const float4*)(featp + b11 + c);
        float e0 = a.x * w00 + b_.x * w01 + gg.x * w10 + d.x * w11;
        float e1 = a.y * w00 + b_.y * w01 + gg.y * w10 + d.y * w11;
        float e2 = a.z * w00 + b_.z * w01 + gg.z * w10 + d.z * w11;
        float e3 = a.w * w00 + b_.w * w01 + gg.w * w10 + d.w * w11;
        fr[c] = e0; fr[c+1] = e1; fr[c+2] = e2; fr[c+3] = e3;
        ss += e0*e0; ss += e1*e1; ss += e2*e2; ss += e3*e3;
    }
    ssq[p][g] = ss;
    __syncthreads();
    float tot = ssq[p][0] + ssq[p][1] + ssq[p][2] + ssq[p][3];
    float inv = 1.0f / fmaxf(sqrtf(tot), 1e-12f);

    if (active) {
        #pragma unroll
        for (int c = 0; c < 16; c += 4) {
            *(float4*)(cn + ob + c) =
                make_float4(fr[c]*inv, fr[c+1]*inv, fr[c+2]*inv, fr[c+3]*inv);
        }
        #pragma unroll
        for (int c = 0; c < 16; c += 4) {
            float4 a  = *(const float4*)(valp + b00 + c);
            float4 b_ = *(const float4*)(valp + b01 + c);
            float4 gg = *(const float4*)(valp + b10 + c);
            float4 d  = *(const float4*)(valp + b11 + c);
            float4 o;
            o.x = a.x * w00 + b_.x * w01 + gg.x * w10 + d.x * w11;
            o.y = a.y * w00 + b_.y * w01 + gg.y * w10 + d.y * w11;
            o.z = a.z * w00 + b_.z * w01 + gg.z * w10 + d.z * w11;
            o.w = a.w * w00 + b_.w * w01 + gg.w * w10 + d.w * w11;
            *(float4*)(vc + ob + c) = o;
        }
    }
}

// ---------------------------------------------------------------------------
// K4a v5: key-per-lane, LDS-free. Each lane owns one key: its 64 normalized
// feat channels live in VGPRs; the center row cn[m][.] is wave-uniform ->
// scalar loads (SGPR) feeding VALU fma directly. Per-lane scalar running
// argmax (strict >, m ascending = reference first-max rule). No barriers.
// Grid (KT2, SPLITS, 4) x 128 = 5184 waves.
// ---------------------------------------------------------------------------
__global__ __launch_bounds__(128) void k4a_sim(
    const float* __restrict__ featp, const float* __restrict__ invn,
    const float* __restrict__ cn, const int* __restrict__ counts,
    const float* __restrict__ alpha_p, const float* __restrict__ beta_p,
    float* __restrict__ part_s, int* __restrict__ part_m)
{
    int r  = blockIdx.z;
    int kt = blockIdx.x;
    int sp = blockIdx.y;
    int t  = threadIdx.x;            // 0..127
    int gk = kt * 128 + t;           // global key in quadrant
    int K  = counts[r];
    int Mr = min(K + 1, MCAP);
    int m0 = (sp * Mr) / SPLITS;     // even center partition, all splits active
    int m1 = ((sp + 1) * Mr) / SPLITS;
    float alpha = alpha_p[0], beta = beta_p[0];

    // B: own key's 64 channels, normalized, in registers (32 x float2)
    vf2 Bv[32];
    {
        float inv = invn[r * QPIX + gk];
        const float4* src = (const float4*)(featp + ((size_t)(r * QPIX + gk)) * 64);
        #pragma unroll
        for (int i = 0; i < 16; i++) {
            float4 fv = src[i];
            Bv[2*i+0].x = fv.x * inv; Bv[2*i+0].y = fv.y * inv;
            Bv[2*i+1].x = fv.z * inv; Bv[2*i+1].y = fv.w * inv;
        }
    }

    float best_s = -INFINITY;
    int   best_m = INT_MAX;
    for (int m = m0; m < m1; m++) {
        // wave-uniform address -> scalar loads
        const vf2* __restrict__ A2 = (const vf2*)(cn + ((size_t)(r * MCAP + m)) * 64);
        vf2 acc0 = {0.0f, 0.0f}, acc1 = {0.0f, 0.0f};
        #pragma unroll
        for (int i = 0; i < 32; i += 2) {
            acc0 += A2[i]     * Bv[i];       // v_pk_fma_f32, SGPR a-operand
            acc1 += A2[i + 1] * Bv[i + 1];
        }
        float dot = (acc0.x + acc1.x) + (acc0.y + acc1.y);
        float s = fmaf(alpha, dot, beta);    // monotone w/ sigmoid
        if (s > best_s) { best_s = s; best_m = m; }
    }

    size_t pb = ((size_t)((r * KT2 + kt) * SPLITS + sp)) * 128;
    part_s[pb + t] = best_s;
    part_m[pb + t] = best_m;
}

// ---------------------------------------------------------------------------
// K4b1: reduce split partials per key (tie -> smaller m), sigmoid, and build
// the center histogram (int atomics only). Grid (KT2, 4) x 128.
// ---------------------------------------------------------------------------
__global__ __launch_bounds__(128) void k4b1_argmax(
    const float* __restrict__ part_s, const int* __restrict__ part_m,
    const int* __restrict__ counts,
    int* __restrict__ win_m, float* __restrict__ win_w, int* __restrict__ cnt)
{
    int r  = blockIdx.y;
    int kt = blockIdx.x;
    int t  = threadIdx.x;
    int gk = kt * 128 + t;
    int K  = counts[r];

    size_t pb = ((size_t)((r * KT2 + kt) * SPLITS)) * 128;
    float bs = -INFINITY; int bm = INT_MAX;
    #pragma unroll 4
    for (int s = 0; s < SPLITS; s++) {
        float s2 = part_s[pb + (size_t)s * 128 + t];
        int   m2 = part_m[pb + (size_t)s * 128 + t];
        if (s2 > bs || (s2 == bs && m2 < bm)) { bs = s2; bm = m2; }
    }
    if (bm < K) {   // skip phantom / empty winners
        win_m[r * QPIX + gk] = bm;
        win_w[r * QPIX + gk] = 1.0f / (1.0f + expf(-bs));
        atomicAdd(&cnt[r * MCAP + bm], 1);
    } else {
        win_m[r * QPIX + gk] = -1;
    }
}

// ---------------------------------------------------------------------------
// K4b2: per-quadrant exclusive scan of the center histogram (CSR bases).
// Grid (4) x 1024; thread handles 3 consecutive centers (3072 = 1024*3).
// ---------------------------------------------------------------------------
__global__ __launch_bounds__(1024) void k4b2_scan(
    const int* __restrict__ cnt, int* __restrict__ base, int* __restrict__ cursor)
{
    __shared__ int wsum[16];
    int r = blockIdx.x;
    int t = threadIdx.x;
    int i0 = r * MCAP + t * 3;
    int v0 = cnt[i0], v1 = cnt[i0 + 1], v2 = cnt[i0 + 2];
    int s = v0 + v1 + v2;
    int lane = t & 63, w = t >> 6;
    int incl = s;
    #pragma unroll
    for (int d = 1; d < 64; d <<= 1) {
        int n = __shfl_up(incl, d, 64);
        if (lane >= d) incl += n;
    }
    if (lane == 63) wsum[w] = incl;
    __syncthreads();
    int wbase = 0;
    for (int i = 0; i < w; i++) wbase += wsum[i];
    int excl = wbase + incl - s;
    base[i0]     = excl;            cursor[i0]     = excl;
    base[i0 + 1] = excl + v0;       cursor[i0 + 1] = excl + v0;
    base[i0 + 2] = excl + v0 + v1;  cursor[i0 + 2] = excl + v0 + v1;
}

// ---------------------------------------------------------------------------
// K4b3: scatter key ids into per-center CSR lists. Grid (KT2, 4) x 128.
// ---------------------------------------------------------------------------
__global__ __launch_bounds__(128) void k4b3_scatter(
    const int* __restrict__ win_m, int* __restrict__ cursor, int* __restrict__ klist)
{
    int r  = blockIdx.y;
    int gk = blockIdx.x * 128 + threadIdx.x;
    int bm = win_m[r * QPIX + gk];
    if (bm >= 0) {
        int pos = atomicAdd(&cursor[r * MCAP + bm], 1);
        klist[r * QPIX + pos] = gk;
    }
}

// ---------------------------------------------------------------------------
// K4c: per-center gather-sum of winner values; non-atomic agg/denom writes.
// One wave per center. Grid (MCAP/4, 4) x 256.
// ---------------------------------------------------------------------------
__global__ __launch_bounds__(256) void k4c_agg(
    const int* __restrict__ cnt, const int* __restrict__ base,
    const int* __restrict__ klist, const float* __restrict__ win_w,
    const float* __restrict__ valp,
    float* __restrict__ agg, float* __restrict__ denom)
{
    int r = blockIdx.y;
    int m = blockIdx.x * 4 + (threadIdx.x >> 6);
    int lane = threadIdx.x & 63;
    int ci = r * MCAP + m;
    int n = cnt[ci];
    if (n == 0) return;              // agg/denom stay zero (k1 zeroed)
    int b = base[ci];
    float acc = 0.0f, ds = 0.0f;
    for (int i = 0; i < n; i++) {
        int gk = klist[r * QPIX + b + i];
        float w = win_w[r * QPIX + gk];
        acc = fmaf(w, valp[((size_t)(r * QPIX + gk)) * 64 + lane], acc);
        ds += w;
    }
    agg[((size_t)ci) * 64 + lane] = acc;
    if (lane == 0) denom[ci] = ds;
}

// ---------------------------------------------------------------------------
// K5: per-point output + projection + transposed store [1,64,1,8192].
// 32 points per block (8 passes of 4) so Wp is staged once per block.
// ---------------------------------------------------------------------------
__global__ __launch_bounds__(256) void k5_out(
    const float* __restrict__ agg, const float* __restrict__ vc,
    const float* __restrict__ denom, const int* __restrict__ slot,
    const float* __restrict__ Wp, const float* __restrict__ bp,
    float* __restrict__ out)
{
    __shared__ float WT[64 * 65];
    __shared__ float ov[4][68];
    __shared__ float res[4][64];
    int t = threadIdx.x;
    {
        int o = t >> 2, cq = (t & 3) * 16;
        #pragma unroll
        for (int i = 0; i < 16; i += 4) {
            float4 wv = *(const float4*)(Wp + o * 64 + cq + i);
            WT[(cq + i + 0) * 65 + o] = wv.x;
            WT[(cq + i + 1) * 65 + o] = wv.y;
            WT[(cq + i + 2) * 65 + o] = wv.z;
            WT[(cq + i + 3) * 65 + o] = wv.w;
        }
    }
    int p = t >> 6, c = t & 63;
    for (int pp = 0; pp < 8; pp++) {
        int n = blockIdx.x * 32 + pp * 4 + p;
        int sl = slot[n];
        float d = denom[sl] + 1.0f;
        float o_v = (agg[(size_t)sl * 64 + c] + vc[(size_t)sl * 64 + c]) / d;
        ov[p][c] = o_v;
        unsigned long long nz = __ballot(o_v != 0.0f);   // wave == point
        __syncthreads();   // ov ready (1st iter: also covers WT staging)
        float acc = bp[c];
        #pragma unroll
        for (int cc = 0; cc < 64; cc++)
            acc = fmaf(ov[p][cc], WT[cc * 65 + c], acc);
        res[p][c] = (nz != 0ull) ? acc : 0.0f;
        __syncthreads();   // res ready; ov reads done before next-pass writes
        if (t < 64) {
            float4 val = make_float4(res[0][t], res[1][t], res[2][t], res[3][t]);
            *(float4*)(out + (size_t)t * NPTS + blockIdx.x * 32 + pp * 4) = val;
        }
    }
}

// ---------------------------------------------------------------------------
extern "C" void kernel_launch(void* const* d_in, const int* in_sizes, int n_in,
                              void* d_out, int out_size, void* d_ws, size_t ws_size,
                              hipStream_t stream) {
    const float* points = (const float*)d_in[0];
    const float* x      = (const float*)d_in[1];
    const float* Wf     = (const float*)d_in[2];
    const float* bf     = (const float*)d_in[3];
    const float* Wv     = (const float*)d_in[4];
    const float* bv     = (const float*)d_in[5];
    const float* Wp     = (const float*)d_in[6];
    const float* bp     = (const float*)d_in[7];
    const float* alpha  = (const float*)d_in[8];
    const float* beta   = (const float*)d_in[9];
    float* out = (float*)d_out;

    float* ws    = (float*)d_ws;
    float* featp = ws;                        // 884736
    float* valp  = featp + 884736;            // 884736
    float* cn    = valp  + 884736;            // 786432 (4*MCAP*64)
    float* vc    = cn    + 786432;            // 786432
    float* agg   = vc    + 786432;            // 786432  (zeroed by k1)
    float* denom = agg   + 786432;            // 12288   (zeroed by k1)
    int*   cnt   = (int*)(denom + 12288);     // 12288   (zeroed by k1)
    float* invn  = (float*)(cnt + 12288);     // 13824
    float* cp    = invn  + 13824;             // 24576 (2*4*MCAP)
    float* part_s= cp    + 24576;             // 331776 (4*27*24*128)
    int*   part_m= (int*)(part_s + 331776);   // 331776
    int*   ccnt  = part_m + 331776;           // 512
    int*   counts= ccnt   + 512;              // 16
    int*   slot  = counts + 16;               // 8192
    int*   win_m = slot   + 8192;             // 13824
    float* win_w = (float*)(win_m + 13824);   // 13824
    int*   basei = (int*)(win_w + 13824);     // 12288
    int*   cursor= basei  + 12288;            // 12288
    int*   klist = cursor + 12288;            // 13824
    // total ~17 MB of d_ws

    k1_linmaps<<<216, 256, 0, stream>>>(x, Wf, bf, Wv, bv, featp, valp, invn, agg);
    k2a_count  <<<128, 64, 0, stream>>>(points, ccnt);
    k2c_scatter<<<128, 64, 0, stream>>>(points, ccnt, cp, slot, counts);
    k3_gather<<<dim3(MCAP / 64, 4), 256, 0, stream>>>(featp, valp, cp, counts, cn, vc);
    k4a_sim<<<dim3(KT2, SPLITS, 4), 128, 0, stream>>>(featp, invn, cn, counts,
                                                      alpha, beta, part_s, part_m);
    k4b1_argmax<<<dim3(KT2, 4), 128, 0, stream>>>(part_s, part_m, counts,
                                                  win_m, win_w, cnt);
    k4b2_scan<<<4, 1024, 0, stream>>>(cnt, basei, cursor);
    k4b3_scatter<<<dim3(KT2, 4), 128, 0, stream>>>(win_m, cursor, klist);
    k4c_agg<<<dim3(MCAP / 4, 4), 256, 0, stream>>>(cnt, basei, klist, win_w,
                                                   valp, agg, denom);
    k5_out<<<NPTS / 32, 256, 0, stream>>>(agg, vc, denom, slot, Wp, bp, out);
}

// Round 6
// 212.225 us; speedup vs baseline: 1.0794x; 1.0794x over previous
//
#include <hip/hip_runtime.h>
#include <math.h>
#include <float.h>
#include <limits.h>

// Problem constants
#define PIX    13824   // 64*216
#define QPIX   3456    // 32*108
#define QW     108
#define QH     32
#define NPTS   8192
#define MCAP   3072    // per-quadrant center capacity (expected ~2048, 26 sigma)
#define KT2    27      // QPIX/128 (k4a key tiles)
#define SPLITS 24      // center splits: one 128-center tile each (covers MCAP)

// ---------------------------------------------------------------------------
// K1: feat/value linear maps + fold to [r][k][c] pixel-major + feat inv-norm.
// Also zeroes agg+denom+cnt (aggregation state) - no separate memset dispatch.
// ---------------------------------------------------------------------------
__global__ __launch_bounds__(256) void k1_linmaps(
    const float* __restrict__ x, const float* __restrict__ Wf, const float* __restrict__ bf,
    const float* __restrict__ Wv, const float* __restrict__ bv,
    float* __restrict__ featp, float* __restrict__ valp, float* __restrict__ invn,
    float* __restrict__ aggz)
{
    __shared__ float ssq[4][64];
    int t = threadIdx.x;

    // zero agg(786432) + denom(12288) + cnt(12288) = 811008 floats = 202752 float4
    {
        float4 z4 = make_float4(0.f, 0.f, 0.f, 0.f);
        for (int i = blockIdx.x * 256 + t; i < 202752; i += 216 * 256)
            ((float4*)aggz)[i] = z4;
    }

    int lane = t & 63;
    int q = t >> 6;                       // wave id -> o-group (wave-uniform)
    int pix = blockIdx.x * 64 + lane;     // 216*64 = 13824 exact
    int h = pix / 216;
    int w = pix - h * 216;
    int r = ((h >> 5) << 1) | (w >= QW ? 1 : 0);
    int k = (h & 31) * QW + (w >= QW ? w - QW : w);

    float xr[64];
    #pragma unroll
    for (int c = 0; c < 64; c++) xr[c] = x[c * PIX + pix];

    size_t base = ((size_t)(r * QPIX + k)) * 64 + q * 16;
    float ss = 0.0f;
    for (int i = 0; i < 16; i++) {
        int o = q * 16 + i;               // wave-uniform
        float af = bf[o], av = bv[o];
        #pragma unroll
        for (int c = 0; c < 64; c++) {
            af = fmaf(Wf[o * 64 + c], xr[c], af);
            av = fmaf(Wv[o * 64 + c], xr[c], av);
        }
        featp[base + i] = af;
        valp[base + i]  = av;
        ss += af * af;
    }
    ssq[q][lane] = ss;
    __syncthreads();
    if (q == 0) {
        float tot = ssq[0][lane] + ssq[1][lane] + ssq[2][lane] + ssq[3][lane];
        invn[r * QPIX + k] = 1.0f / fmaxf(sqrtf(tot), 1e-12f);
    }
}

// ---------------------------------------------------------------------------
// K2 (order-preserving compaction):
//   k2a: per-64-point-chunk quadrant counts (128 chunks)
//   k2c: per-block redundant scan of chunk counts + ranked scatter
// ---------------------------------------------------------------------------
__device__ __forceinline__ int point_quadrant(float px, float py) {
    // rh = 384/2 = 192 exact, rw = 1296/2 = 648 exact
    return ((py > 192.0f) ? 2 : 0) + ((px > 648.0f) ? 1 : 0);
}

__global__ __launch_bounds__(64) void k2a_count(
    const float* __restrict__ points, int* __restrict__ ccnt)
{
    int lane = threadIdx.x;
    int chunk = blockIdx.x;
    float2 p = ((const float2*)points)[chunk * 64 + lane];
    int q = point_quadrant(p.x, p.y);
    #pragma unroll
    for (int r = 0; r < 4; r++) {
        unsigned long long m = __ballot(q == r);
        if (lane == 0) ccnt[chunk * 4 + r] = __popcll(m);
    }
}

__global__ __launch_bounds__(64) void k2c_scatter(
    const float* __restrict__ points, const int* __restrict__ ccnt,
    float* __restrict__ cp, int* __restrict__ slot, int* __restrict__ counts)
{
    int lane = threadIdx.x;
    int chunk = blockIdx.x;

    // redundant per-block scan: prefix over chunks < my chunk, per quadrant
    int c0[4], c1[4], pre[4];
    #pragma unroll
    for (int r = 0; r < 4; r++) {
        c0[r] = ccnt[lane * 4 + r];
        c1[r] = ccnt[(lane + 64) * 4 + r];
        pre[r] = (lane < chunk ? c0[r] : 0) + (lane + 64 < chunk ? c1[r] : 0);
    }
    #pragma unroll
    for (int d = 1; d < 64; d <<= 1) {
        #pragma unroll
        for (int r = 0; r < 4; r++) pre[r] += __shfl_xor(pre[r], d, 64);
    }
    if (chunk == 0) {   // block 0 also publishes the totals
        int full[4];
        #pragma unroll
        for (int r = 0; r < 4; r++) full[r] = c0[r] + c1[r];
        #pragma unroll
        for (int d = 1; d < 64; d <<= 1) {
            #pragma unroll
            for (int r = 0; r < 4; r++) full[r] += __shfl_xor(full[r], d, 64);
        }
        if (lane == 0) {
            #pragma unroll
            for (int r = 0; r < 4; r++) counts[r] = full[r];
        }
    }

    int n = chunk * 64 + lane;
    float2 p = ((const float2*)points)[n];
    int q = point_quadrant(p.x, p.y);
    unsigned long long below = (lane == 0) ? 0ull : (~0ull >> (64 - lane));
    #pragma unroll
    for (int r = 0; r < 4; r++) {
        unsigned long long m = __ballot(q == r);
        if (q == r) {
            int pos = pre[r] + __popcll(m & below);
            ((float2*)cp)[r * MCAP + pos] = p;
            slot[n] = r * MCAP + pos;
        }
    }
}

// ---------------------------------------------------------------------------
// K3: bilinear gather (border clamp) of feat & value at compacted points;
// slot m == K_r is the phantom (0,0) padded row. 4 channel-groups per point
// (256-thread blocks, 16 ch/thread).
// ---------------------------------------------------------------------------
__global__ __launch_bounds__(256) void k3_gather(
    const float* __restrict__ featp, const float* __restrict__ valp,
    const float* __restrict__ cp, const int* __restrict__ counts,
    float* __restrict__ cn, float* __restrict__ vc)
{
    __shared__ float ssq[64][5];
    int r = blockIdx.y;
    int t = threadIdx.x;
    int g = t & 3, p = t >> 2;          // g: channel group, p: point in tile
    int m = blockIdx.x * 64 + p;
    int K = counts[r];
    int Mr = min(K + 1, MCAP);
    bool active = m < Mr;

    float px = 0.0f, py = 0.0f;
    if (m < K) { float2 pt = ((const float2*)cp)[r * MCAP + m]; px = pt.x; py = pt.y; }

    // mirror reference op order: grid = p/(S-1)*2-1 ; g = (grid+1)*(D/2)-0.5
    float gx = (px / 1295.0f * 2.0f - 1.0f + 1.0f) * 54.0f - 0.5f;
    float gy = (py / 383.0f  * 2.0f - 1.0f + 1.0f) * 16.0f - 0.5f;
    float x0 = floorf(gx), y0 = floorf(gy);
    float wx = gx - x0, wy = gy - y0;
    int x0i = (int)fminf(fmaxf(x0,         0.0f), 107.0f);
    int x1i = (int)fminf(fmaxf(x0 + 1.0f,  0.0f), 107.0f);
    int y0i = (int)fminf(fmaxf(y0,         0.0f), 31.0f);
    int y1i = (int)fminf(fmaxf(y0 + 1.0f,  0.0f), 31.0f);
    float w00 = (1.0f - wx) * (1.0f - wy);
    float w01 = wx * (1.0f - wy);
    float w10 = (1.0f - wx) * wy;
    float w11 = wx * wy;

    int c0 = g * 16;
    size_t b00 = ((size_t)(r * QPIX + y0i * QW + x0i)) * 64 + c0;
    size_t b01 = ((size_t)(r * QPIX + y0i * QW + x1i)) * 64 + c0;
    size_t b10 = ((size_t)(r * QPIX + y1i * QW + x0i)) * 64 + c0;
    size_t b11 = ((size_t)(r * QPIX + y1i * QW + x1i)) * 64 + c0;
    size_t ob  = ((size_t)(r * MCAP + m)) * 64 + c0;

    float fr[16];
    float ss = 0.0f;
    #pragma unroll
    for (int c = 0; c < 16; c += 4) {
        float4 a  = *(const float4*)(featp + b00 + c);
        float4 b_ = *(const float4*)(featp + b01 + c);
        float4 gg = *(const float4*)(featp + b10 + c);
        float4 d  = *(const float4*)(featp + b11 + c);
        float e0 = a.x * w00 + b_.x * w01 + gg.x * w10 + d.x * w11;
        float e1 = a.y * w00 + b_.y * w01 + gg.y * w10 + d.y * w11;
        float e2 = a.z * w00 + b_.z * w01 + gg.z * w10 + d.z * w11;
        float e3 = a.w * w00 + b_.w * w01 + gg.w * w10 + d.w * w11;
        fr[c] = e0; fr[c+1] = e1; fr[c+2] = e2; fr[c+3] = e3;
        ss += e0*e0; ss += e1*e1; ss += e2*e2; ss += e3*e3;
    }
    ssq[p][g] = ss;
    __syncthreads();
    float tot = ssq[p][0] + ssq[p][1] + ssq[p][2] + ssq[p][3];
    float inv = 1.0f / fmaxf(sqrtf(tot), 1e-12f);

    if (active) {
        #pragma unroll
        for (int c = 0; c < 16; c += 4) {
            *(float4*)(cn + ob + c) =
                make_float4(fr[c]*inv, fr[c+1]*inv, fr[c+2]*inv, fr[c+3]*inv);
        }
        #pragma unroll
        for (int c = 0; c < 16; c += 4) {
            float4 a  = *(const float4*)(valp + b00 + c);
            float4 b_ = *(const float4*)(valp + b01 + c);
            float4 gg = *(const float4*)(valp + b10 + c);
            float4 d  = *(const float4*)(valp + b11 + c);
            float4 o;
            o.x = a.x * w00 + b_.x * w01 + gg.x * w10 + d.x * w11;
            o.y = a.y * w00 + b_.y * w01 + gg.y * w10 + d.y * w11;
            o.z = a.z * w00 + b_.z * w01 + gg.z * w10 + d.z * w11;
            o.w = a.w * w00 + b_.w * w01 + gg.w * w10 + d.w * w11;
            *(float4*)(vc + ob + c) = o;
        }
    }
}

// ---------------------------------------------------------------------------
// K4a v6: cosine-sim running argmax. 128 keys x 128 centers per block (one
// tile). Frag 8x8 (F=64 FMA, R=4 ds_read_b128 per cc -> LDS/VALU=1.5, vs 2.25
// at R4's 4x8). Key cols split tx*4 / 64+tx*4 and center rows ty*4 / 64+ty*4:
// every LDS read is <=2-way bank aliased or a broadcast (free). LDS 64 KiB ->
// 2 blocks/CU; cross-block overlap hides staging. Grid (KT2, SPLITS, 4) x 256.
// ---------------------------------------------------------------------------
__global__ __launch_bounds__(256) void k4a_sim(
    const float* __restrict__ featp, const float* __restrict__ invn,
    const float* __restrict__ cn, const int* __restrict__ counts,
    const float* __restrict__ alpha_p, const float* __restrict__ beta_p,
    float* __restrict__ part_s, int* __restrict__ part_m)
{
    __shared__ float Bt[64 * 128];   // [ch][key]     32 KiB
    __shared__ float At[64 * 128];   // [ch][center]  32 KiB

    int r  = blockIdx.z;
    int kt = blockIdx.x;
    int sp = blockIdx.y;             // one 128-center tile
    int k0 = kt * 128;
    int t  = threadIdx.x;
    int tx = t & 15, ty = t >> 4;    // tx -> 8 keys, ty -> 8 centers
    int K  = counts[r];
    int Mr = min(K + 1, MCAP);
    int ntiles = (Mr + 127) >> 7;
    if (sp >= ntiles) return;        // k4b1 only reads partials for sp < ntiles
    float alpha = alpha_p[0], beta = beta_p[0];

    // stage B tile: 128 keys x 64 ch, normalized, channel-major
    {
        int j = t >> 1, hh = (t & 1) * 32;
        float inv = invn[r * QPIX + k0 + j];
        const float* src = featp + ((size_t)(r * QPIX + k0 + j)) * 64 + hh;
        #pragma unroll
        for (int i = 0; i < 32; i += 4) {
            float4 fv = *(const float4*)(src + i);
            Bt[(hh + i + 0) * 128 + j] = fv.x * inv;
            Bt[(hh + i + 1) * 128 + j] = fv.y * inv;
            Bt[(hh + i + 2) * 128 + j] = fv.z * inv;
            Bt[(hh + i + 3) * 128 + j] = fv.w * inv;
        }
    }
    // stage A tile: 128 centers x 64 ch, channel-major
    {
        int j = t >> 1, hh = (t & 1) * 32;
        int mg = min(sp * 128 + j, MCAP - 1);
        const float* src = cn + ((size_t)(r * MCAP + mg)) * 64 + hh;
        #pragma unroll
        for (int i = 0; i < 32; i += 4) {
            float4 fv = *(const float4*)(src + i);
            At[(hh + i + 0) * 128 + j] = fv.x;
            At[(hh + i + 1) * 128 + j] = fv.y;
            At[(hh + i + 2) * 128 + j] = fv.z;
            At[(hh + i + 3) * 128 + j] = fv.w;
        }
    }
    __syncthreads();

    float dot[8][8] = {};
    #pragma unroll 2
    for (int cc = 0; cc < 64; cc++) {
        float4 a0 = *(const float4*)(At + cc * 128 + ty * 4);
        float4 a1 = *(const float4*)(At + cc * 128 + 64 + ty * 4);
        float4 b0 = *(const float4*)(Bt + cc * 128 + tx * 4);
        float4 b1 = *(const float4*)(Bt + cc * 128 + 64 + tx * 4);
        float a[8] = {a0.x, a0.y, a0.z, a0.w, a1.x, a1.y, a1.z, a1.w};
        float b[8] = {b0.x, b0.y, b0.z, b0.w, b1.x, b1.y, b1.z, b1.w};
        #pragma unroll
        for (int u = 0; u < 8; u++) {
            #pragma unroll
            for (int v = 0; v < 8; v++)
                dot[u][v] = fmaf(a[u], b[v], dot[u][v]);
        }
    }

    // running argmax; m ascending in u (u>>2 selects the 64-row half);
    // strict > keeps smallest m on exact fp32 ties (reference first-max rule)
    float best_s[8];
    int   best_m[8];
    #pragma unroll
    for (int v = 0; v < 8; v++) { best_s[v] = -INFINITY; best_m[v] = INT_MAX; }
    #pragma unroll
    for (int u = 0; u < 8; u++) {
        int mg = sp * 128 + ((u >> 2) << 6) + ty * 4 + (u & 3);
        bool valid = mg < Mr;
        #pragma unroll
        for (int v = 0; v < 8; v++) {
            float s = fmaf(alpha, dot[u][v], beta);  // monotone w/ sigmoid
            if (valid && s > best_s[v]) { best_s[v] = s; best_m[v] = mg; }
        }
    }

    // cross-thread (ty) reduce per key; tie -> smaller m; store partials.
    // Reuse Bt as [16][128] scratch after all compute reads are done.
    __syncthreads();
    float* rs = Bt;
    int*   rm = (int*)(Bt + 2048);
    #pragma unroll
    for (int v = 0; v < 8; v++) {
        int col = ((v >> 2) << 6) + tx * 4 + (v & 3);   // key column of this best
        rs[ty * 128 + col] = best_s[v];
        rm[ty * 128 + col] = best_m[v];
    }
    __syncthreads();
    if (t < 128) {
        float bs = rs[t]; int bm = rm[t];
        #pragma unroll
        for (int y = 1; y < 16; y++) {
            float s2 = rs[y * 128 + t]; int m2 = rm[y * 128 + t];
            if (s2 > bs || (s2 == bs && m2 < bm)) { bs = s2; bm = m2; }
        }
        size_t pb = ((size_t)((r * KT2 + kt) * SPLITS + sp)) * 128;
        part_s[pb + t] = bs;
        part_m[pb + t] = bm;
    }
}

// ---------------------------------------------------------------------------
// K4b1: reduce split partials per key (tie -> smaller m), sigmoid, and build
// the center histogram (int atomics only). Grid (KT2, 4) x 128.
// ---------------------------------------------------------------------------
__global__ __launch_bounds__(128) void k4b1_argmax(
    const float* __restrict__ part_s, const int* __restrict__ part_m,
    const int* __restrict__ counts,
    int* __restrict__ win_m, float* __restrict__ win_w, int* __restrict__ cnt)
{
    int r  = blockIdx.y;
    int kt = blockIdx.x;
    int t  = threadIdx.x;
    int gk = kt * 128 + t;
    int K  = counts[r];
    int Mr = min(K + 1, MCAP);
    int nS = (Mr + 127) >> 7;   // active splits (one 128-center tile each)

    size_t pb = ((size_t)((r * KT2 + kt) * SPLITS)) * 128;
    float bs = -INFINITY; int bm = INT_MAX;
    for (int s = 0; s < nS; s++) {
        float s2 = part_s[pb + (size_t)s * 128 + t];
        int   m2 = part_m[pb + (size_t)s * 128 + t];
        if (s2 > bs || (s2 == bs && m2 < bm)) { bs = s2; bm = m2; }
    }
    if (bm < K) {   // skip phantom / empty winners
        win_m[r * QPIX + gk] = bm;
        win_w[r * QPIX + gk] = 1.0f / (1.0f + expf(-bs));
        atomicAdd(&cnt[r * MCAP + bm], 1);
    } else {
        win_m[r * QPIX + gk] = -1;
    }
}

// ---------------------------------------------------------------------------
// K4b2: per-quadrant exclusive scan of the center histogram (CSR bases).
// Grid (4) x 1024; thread handles 3 consecutive centers (3072 = 1024*3).
// ---------------------------------------------------------------------------
__global__ __launch_bounds__(1024) void k4b2_scan(
    const int* __restrict__ cnt, int* __restrict__ base, int* __restrict__ cursor)
{
    __shared__ int wsum[16];
    int r = blockIdx.x;
    int t = threadIdx.x;
    int i0 = r * MCAP + t * 3;
    int v0 = cnt[i0], v1 = cnt[i0 + 1], v2 = cnt[i0 + 2];
    int s = v0 + v1 + v2;
    int lane = t & 63, w = t >> 6;
    int incl = s;
    #pragma unroll
    for (int d = 1; d < 64; d <<= 1) {
        int n = __shfl_up(incl, d, 64);
        if (lane >= d) incl += n;
    }
    if (lane == 63) wsum[w] = incl;
    __syncthreads();
    int wbase = 0;
    for (int i = 0; i < w; i++) wbase += wsum[i];
    int excl = wbase + incl - s;
    base[i0]     = excl;            cursor[i0]     = excl;
    base[i0 + 1] = excl + v0;       cursor[i0 + 1] = excl + v0;
    base[i0 + 2] = excl + v0 + v1;  cursor[i0 + 2] = excl + v0 + v1;
}

// ---------------------------------------------------------------------------
// K4b3: scatter key ids into per-center CSR lists. Grid (KT2, 4) x 128.
// ---------------------------------------------------------------------------
__global__ __launch_bounds__(128) void k4b3_scatter(
    const int* __restrict__ win_m, int* __restrict__ cursor, int* __restrict__ klist)
{
    int r  = blockIdx.y;
    int gk = blockIdx.x * 128 + threadIdx.x;
    int bm = win_m[r * QPIX + gk];
    if (bm >= 0) {
        int pos = atomicAdd(&cursor[r * MCAP + bm], 1);
        klist[r * QPIX + pos] = gk;
    }
}

// ---------------------------------------------------------------------------
// K4c: per-center gather-sum of winner values; non-atomic agg/denom writes.
// One wave per center. Grid (MCAP/4, 4) x 256.
// ---------------------------------------------------------------------------
__global__ __launch_bounds__(256) void k4c_agg(
    const int* __restrict__ cnt, const int* __restrict__ base,
    const int* __restrict__ klist, const float* __restrict__ win_w,
    const float* __restrict__ valp,
    float* __restrict__ agg, float* __restrict__ denom)
{
    int r = blockIdx.y;
    int m = blockIdx.x * 4 + (threadIdx.x >> 6);
    int lane = threadIdx.x & 63;
    int ci = r * MCAP + m;
    int n = cnt[ci];
    if (n == 0) return;              // agg/denom stay zero (k1 zeroed)
    int b = base[ci];
    float acc = 0.0f, ds = 0.0f;
    for (int i = 0; i < n; i++) {
        int gk = klist[r * QPIX + b + i];
        float w = win_w[r * QPIX + gk];
        acc = fmaf(w, valp[((size_t)(r * QPIX + gk)) * 64 + lane], acc);
        ds += w;
    }
    agg[((size_t)ci) * 64 + lane] = acc;
    if (lane == 0) denom[ci] = ds;
}

// ---------------------------------------------------------------------------
// K5: per-point output + projection + transposed store [1,64,1,8192].
// 32 points per block (8 passes of 4) so Wp is staged once per block.
// ---------------------------------------------------------------------------
__global__ __launch_bounds__(256) void k5_out(
    const float* __restrict__ agg, const float* __restrict__ vc,
    const float* __restrict__ denom, const int* __restrict__ slot,
    const float* __restrict__ Wp, const float* __restrict__ bp,
    float* __restrict__ out)
{
    __shared__ float WT[64 * 65];
    __shared__ float ov[4][68];
    __shared__ float res[4][64];
    int t = threadIdx.x;
    {
        int o = t >> 2, cq = (t & 3) * 16;
        #pragma unroll
        for (int i = 0; i < 16; i += 4) {
            float4 wv = *(const float4*)(Wp + o * 64 + cq + i);
            WT[(cq + i + 0) * 65 + o] = wv.x;
            WT[(cq + i + 1) * 65 + o] = wv.y;
            WT[(cq + i + 2) * 65 + o] = wv.z;
            WT[(cq + i + 3) * 65 + o] = wv.w;
        }
    }
    int p = t >> 6, c = t & 63;
    for (int pp = 0; pp < 8; pp++) {
        int n = blockIdx.x * 32 + pp * 4 + p;
        int sl = slot[n];
        float d = denom[sl] + 1.0f;
        float o_v = (agg[(size_t)sl * 64 + c] + vc[(size_t)sl * 64 + c]) / d;
        ov[p][c] = o_v;
        unsigned long long nz = __ballot(o_v != 0.0f);   // wave == point
        __syncthreads();   // ov ready (1st iter: also covers WT staging)
        float acc = bp[c];
        #pragma unroll
        for (int cc = 0; cc < 64; cc++)
            acc = fmaf(ov[p][cc], WT[cc * 65 + c], acc);
        res[p][c] = (nz != 0ull) ? acc : 0.0f;
        __syncthreads();   // res ready; ov reads done before next-pass writes
        if (t < 64) {
            float4 val = make_float4(res[0][t], res[1][t], res[2][t], res[3][t]);
            *(float4*)(out + (size_t)t * NPTS + blockIdx.x * 32 + pp * 4) = val;
        }
    }
}

// ---------------------------------------------------------------------------
extern "C" void kernel_launch(void* const* d_in, const int* in_sizes, int n_in,
                              void* d_out, int out_size, void* d_ws, size_t ws_size,
                              hipStream_t stream) {
    const float* points = (const float*)d_in[0];
    const float* x      = (const float*)d_in[1];
    const float* Wf     = (const float*)d_in[2];
    const float* bf     = (const float*)d_in[3];
    const float* Wv     = (const float*)d_in[4];
    const float* bv     = (const float*)d_in[5];
    const float* Wp     = (const float*)d_in[6];
    const float* bp     = (const float*)d_in[7];
    const float* alpha  = (const float*)d_in[8];
    const float* beta   = (const float*)d_in[9];
    float* out = (float*)d_out;

    float* ws    = (float*)d_ws;
    float* featp = ws;                        // 884736
    float* valp  = featp + 884736;            // 884736
    float* cn    = valp  + 884736;            // 786432 (4*MCAP*64)
    float* vc    = cn    + 786432;            // 786432
    float* agg   = vc    + 786432;            // 786432  (zeroed by k1)
    float* denom = agg   + 786432;            // 12288   (zeroed by k1)
    int*   cnt   = (int*)(denom + 12288);     // 12288   (zeroed by k1)
    float* invn  = (float*)(cnt + 12288);     // 13824
    float* cp    = invn  + 13824;             // 24576 (2*4*MCAP)
    float* part_s= cp    + 24576;             // 331776 (4*27*24*128)
    int*   part_m= (int*)(part_s + 331776);   // 331776
    int*   ccnt  = part_m + 331776;           // 512
    int*   counts= ccnt   + 512;              // 16
    int*   slot  = counts + 16;               // 8192
    int*   win_m = slot   + 8192;             // 13824
    float* win_w = (float*)(win_m + 13824);   // 13824
    int*   basei = (int*)(win_w + 13824);     // 12288
    int*   cursor= basei  + 12288;            // 12288
    int*   klist = cursor + 12288;            // 13824
    // total ~17 MB of d_ws

    k1_linmaps<<<216, 256, 0, stream>>>(x, Wf, bf, Wv, bv, featp, valp, invn, agg);
    k2a_count  <<<128, 64, 0, stream>>>(points, ccnt);
    k2c_scatter<<<128, 64, 0, stream>>>(points, ccnt, cp, slot, counts);
    k3_gather<<<dim3(MCAP / 64, 4), 256, 0, stream>>>(featp, valp, cp, counts, cn, vc);
    k4a_sim<<<dim3(KT2, SPLITS, 4), 256, 0, stream>>>(featp, invn, cn, counts,
                                                      alpha, beta, part_s, part_m);
    k4b1_argmax<<<dim3(KT2, 4), 128, 0, stream>>>(part_s, part_m, counts,
                                                  win_m, win_w, cnt);
    k4b2_scan<<<4, 1024, 0, stream>>>(cnt, basei, cursor);
    k4b3_scatter<<<dim3(KT2, 4), 128, 0, stream>>>(win_m, cursor, klist);
    k4c_agg<<<dim3(MCAP / 4, 4), 256, 0, stream>>>(cnt, basei, klist, win_w,
                                                   valp, agg, denom);
    k5_out<<<NPTS / 32, 256, 0, stream>>>(agg, vc, denom, slot, Wp, bp, out);
}

// Round 7
// 208.382 us; speedup vs baseline: 1.0993x; 1.0184x over previous
//
#include <hip/hip_runtime.h>
#include <math.h>
#include <float.h>
#include <limits.h>

// Problem constants
#define PIX    13824   // 64*216
#define QPIX   3456    // 32*108
#define QW     108
#define QH     32
#define NPTS   8192
#define MCAP   3072    // per-quadrant center capacity (expected ~2048, 26 sigma)
#define KT2    27      // QPIX/128 (k4a key tiles)
#define CSPL   24      // center-splits: each block 2 x 64-center tiles

// ---------------------------------------------------------------------------
// K1: feat/value linear maps + fold to [r][k][c] pixel-major + feat inv-norm.
// 512 threads: 8 waves x 8 outputs (2 waves/SIMD vs 1 before).
// Also zeroes agg+denom - no separate memset dispatch.
// ---------------------------------------------------------------------------
__global__ __launch_bounds__(512) void k1_linmaps(
    const float* __restrict__ x, const float* __restrict__ Wf, const float* __restrict__ bf,
    const float* __restrict__ Wv, const float* __restrict__ bv,
    float* __restrict__ featp, float* __restrict__ valp, float* __restrict__ invn,
    float* __restrict__ aggz)
{
    __shared__ float ssq[8][64];
    int t = threadIdx.x;

    // zero agg(786432) + denom(12288) = 798720 floats = 199680 float4
    {
        float4 z4 = make_float4(0.f, 0.f, 0.f, 0.f);
        for (int i = blockIdx.x * 512 + t; i < 199680; i += 216 * 512)
            ((float4*)aggz)[i] = z4;
    }

    int lane = t & 63;
    int q = t >> 6;                       // wave id -> o-group of 8 (wave-uniform)
    int pix = blockIdx.x * 64 + lane;     // 216*64 = 13824 exact
    int h = pix / 216;
    int w = pix - h * 216;
    int r = ((h >> 5) << 1) | (w >= QW ? 1 : 0);
    int k = (h & 31) * QW + (w >= QW ? w - QW : w);

    float xr[64];
    #pragma unroll
    for (int c = 0; c < 64; c++) xr[c] = x[c * PIX + pix];

    size_t base = ((size_t)(r * QPIX + k)) * 64 + q * 8;
    float ss = 0.0f;
    for (int i = 0; i < 8; i++) {
        int o = q * 8 + i;                // wave-uniform
        float af = bf[o], av = bv[o];
        #pragma unroll
        for (int c = 0; c < 64; c++) {
            af = fmaf(Wf[o * 64 + c], xr[c], af);
            av = fmaf(Wv[o * 64 + c], xr[c], av);
        }
        featp[base + i] = af;
        valp[base + i]  = av;
        ss += af * af;
    }
    ssq[q][lane] = ss;
    __syncthreads();
    if (q == 0) {
        float tot = 0.0f;
        #pragma unroll
        for (int i = 0; i < 8; i++) tot += ssq[i][lane];
        invn[r * QPIX + k] = 1.0f / fmaxf(sqrtf(tot), 1e-12f);
    }
}

// ---------------------------------------------------------------------------
// K2 (order-preserving compaction):
//   k2a: per-64-point-chunk quadrant counts (128 chunks)
//   k2c: per-block redundant scan of chunk counts + ranked scatter
// ---------------------------------------------------------------------------
__device__ __forceinline__ int point_quadrant(float px, float py) {
    // rh = 384/2 = 192 exact, rw = 1296/2 = 648 exact
    return ((py > 192.0f) ? 2 : 0) + ((px > 648.0f) ? 1 : 0);
}

__global__ __launch_bounds__(64) void k2a_count(
    const float* __restrict__ points, int* __restrict__ ccnt)
{
    int lane = threadIdx.x;
    int chunk = blockIdx.x;
    float2 p = ((const float2*)points)[chunk * 64 + lane];
    int q = point_quadrant(p.x, p.y);
    #pragma unroll
    for (int r = 0; r < 4; r++) {
        unsigned long long m = __ballot(q == r);
        if (lane == 0) ccnt[chunk * 4 + r] = __popcll(m);
    }
}

__global__ __launch_bounds__(64) void k2c_scatter(
    const float* __restrict__ points, const int* __restrict__ ccnt,
    float* __restrict__ cp, int* __restrict__ slot, int* __restrict__ counts)
{
    int lane = threadIdx.x;
    int chunk = blockIdx.x;

    // redundant per-block scan: prefix over chunks < my chunk, per quadrant
    int c0[4], c1[4], pre[4];
    #pragma unroll
    for (int r = 0; r < 4; r++) {
        c0[r] = ccnt[lane * 4 + r];
        c1[r] = ccnt[(lane + 64) * 4 + r];
        pre[r] = (lane < chunk ? c0[r] : 0) + (lane + 64 < chunk ? c1[r] : 0);
    }
    #pragma unroll
    for (int d = 1; d < 64; d <<= 1) {
        #pragma unroll
        for (int r = 0; r < 4; r++) pre[r] += __shfl_xor(pre[r], d, 64);
    }
    if (chunk == 0) {   // block 0 also publishes the totals
        int full[4];
        #pragma unroll
        for (int r = 0; r < 4; r++) full[r] = c0[r] + c1[r];
        #pragma unroll
        for (int d = 1; d < 64; d <<= 1) {
            #pragma unroll
            for (int r = 0; r < 4; r++) full[r] += __shfl_xor(full[r], d, 64);
        }
        if (lane == 0) {
            #pragma unroll
            for (int r = 0; r < 4; r++) counts[r] = full[r];
        }
    }

    int n = chunk * 64 + lane;
    float2 p = ((const float2*)points)[n];
    int q = point_quadrant(p.x, p.y);
    unsigned long long below = (lane == 0) ? 0ull : (~0ull >> (64 - lane));
    #pragma unroll
    for (int r = 0; r < 4; r++) {
        unsigned long long m = __ballot(q == r);
        if (q == r) {
            int pos = pre[r] + __popcll(m & below);
            ((float2*)cp)[r * MCAP + pos] = p;
            slot[n] = r * MCAP + pos;
        }
    }
}

// ---------------------------------------------------------------------------
// K3: bilinear gather (border clamp) of feat & value at compacted points;
// slot m == K_r is the phantom (0,0) padded row. 8 channel-groups x 32 points
// per block (256 threads, 8 ch/thread) - 2x waves vs 16-ch version.
// ---------------------------------------------------------------------------
__global__ __launch_bounds__(256) void k3_gather(
    const float* __restrict__ featp, const float* __restrict__ valp,
    const float* __restrict__ cp, const int* __restrict__ counts,
    float* __restrict__ cn, float* __restrict__ vc)
{
    __shared__ float ssq[32][9];
    int r = blockIdx.y;
    int t = threadIdx.x;
    int g = t & 7, p = t >> 3;          // g: channel group (8ch), p: point in tile
    int m = blockIdx.x * 32 + p;
    int K = counts[r];
    int Mr = min(K + 1, MCAP);
    bool active = m < Mr;

    float px = 0.0f, py = 0.0f;
    if (m < K) { float2 pt = ((const float2*)cp)[r * MCAP + m]; px = pt.x; py = pt.y; }

    // mirror reference op order: grid = p/(S-1)*2-1 ; g = (grid+1)*(D/2)-0.5
    float gx = (px / 1295.0f * 2.0f - 1.0f + 1.0f) * 54.0f - 0.5f;
    float gy = (py / 383.0f  * 2.0f - 1.0f + 1.0f) * 16.0f - 0.5f;
    float x0 = floorf(gx), y0 = floorf(gy);
    float wx = gx - x0, wy = gy - y0;
    int x0i = (int)fminf(fmaxf(x0,         0.0f), 107.0f);
    int x1i = (int)fminf(fmaxf(x0 + 1.0f,  0.0f), 107.0f);
    int y0i = (int)fminf(fmaxf(y0,         0.0f), 31.0f);
    int y1i = (int)fminf(fmaxf(y0 + 1.0f,  0.0f), 31.0f);
    float w00 = (1.0f - wx) * (1.0f - wy);
    float w01 = wx * (1.0f - wy);
    float w10 = (1.0f - wx) * wy;
    float w11 = wx * wy;

    int c0 = g * 8;
    size_t b00 = ((size_t)(r * QPIX + y0i * QW + x0i)) * 64 + c0;
    size_t b01 = ((size_t)(r * QPIX + y0i * QW + x1i)) * 64 + c0;
    size_t b10 = ((size_t)(r * QPIX + y1i * QW + x0i)) * 64 + c0;
    size_t b11 = ((size_t)(r * QPIX + y1i * QW + x1i)) * 64 + c0;
    size_t ob  = ((size_t)(r * MCAP + m)) * 64 + c0;

    float fr[8];
    float ss = 0.0f;
    #pragma unroll
    for (int c = 0; c < 8; c += 4) {
        float4 a  = *(const float4*)(featp + b00 + c);
        float4 b_ = *(const float4*)(featp + b01 + c);
        float4 gg = *(const float4*)(featp + b10 + c);
        float4 d  = *(const float4*)(featp + b11 + c);
        float e0 = a.x * w00 + b_.x * w01 + gg.x * w10 + d.x * w11;
        float e1 = a.y * w00 + b_.y * w01 + gg.y * w10 + d.y * w11;
        float e2 = a.z * w00 + b_.z * w01 + gg.z * w10 + d.z * w11;
        float e3 = a.w * w00 + b_.w * w01 + gg.w * w10 + d.w * w11;
        fr[c] = e0; fr[c+1] = e1; fr[c+2] = e2; fr[c+3] = e3;
        ss += e0*e0; ss += e1*e1; ss += e2*e2; ss += e3*e3;
    }
    ssq[p][g] = ss;
    __syncthreads();
    float tot = 0.0f;
    #pragma unroll
    for (int i = 0; i < 8; i++) tot += ssq[p][i];
    float inv = 1.0f / fmaxf(sqrtf(tot), 1e-12f);

    if (active) {
        #pragma unroll
        for (int c = 0; c < 8; c += 4) {
            *(float4*)(cn + ob + c) =
                make_float4(fr[c]*inv, fr[c+1]*inv, fr[c+2]*inv, fr[c+3]*inv);
        }
        #pragma unroll
        for (int c = 0; c < 8; c += 4) {
            float4 a  = *(const float4*)(valp + b00 + c);
            float4 b_ = *(const float4*)(valp + b01 + c);
            float4 gg = *(const float4*)(valp + b10 + c);
            float4 d  = *(const float4*)(valp + b11 + c);
            float4 o;
            o.x = a.x * w00 + b_.x * w01 + gg.x * w10 + d.x * w11;
            o.y = a.y * w00 + b_.y * w01 + gg.y * w10 + d.y * w11;
            o.z = a.z * w00 + b_.z * w01 + gg.z * w10 + d.z * w11;
            o.w = a.w * w00 + b_.w * w01 + gg.w * w10 + d.w * w11;
            *(float4*)(vc + ob + c) = o;
        }
    }
}

// ---------------------------------------------------------------------------
// K4a v7: R4 structure (128 keys x 64 centers/tile, 2 tiles/block, frag 4x8,
// LDS 48 KiB -> 3 blocks/CU) + software-pipelined A staging: next tile's
// global loads issue BEFORE compute so L2 latency hides under the 64-cc loop.
// All LDS reads <=2-way bank aliased (free). Grid (KT2, CSPL, 4) x 256.
// ---------------------------------------------------------------------------
__global__ __launch_bounds__(256) void k4a_sim(
    const float* __restrict__ featp, const float* __restrict__ invn,
    const float* __restrict__ cn, const int* __restrict__ counts,
    const float* __restrict__ alpha_p, const float* __restrict__ beta_p,
    float* __restrict__ part_s, int* __restrict__ part_m)
{
    __shared__ float Bt[64 * 128];   // [ch][key]     32 KiB
    __shared__ float At[64 * 64];    // [ch][center]  16 KiB

    int r  = blockIdx.z;
    int kt = blockIdx.x;
    int sp = blockIdx.y;
    int k0 = kt * 128;
    int t  = threadIdx.x;
    int tx = t & 15, ty = t >> 4;    // tx -> 8 keys (2 groups of 4), ty -> 4 centers
    int K  = counts[r];
    int Mr = min(K + 1, MCAP);
    int ntiles = (Mr + 63) >> 6;
    int ct0 = sp * 2;
    if (ct0 >= ntiles) return;       // k4b only reads partials for sp < ceil(ntiles/2)
    int ctEnd = min(ct0 + 2, ntiles);
    float alpha = alpha_p[0], beta = beta_p[0];

    // stage B tile: 128 keys x 64 ch, normalized, channel-major
    {
        int j = t >> 1, hh = (t & 1) * 32;
        float inv = invn[r * QPIX + k0 + j];
        const float* src = featp + ((size_t)(r * QPIX + k0 + j)) * 64 + hh;
        #pragma unroll
        for (int i = 0; i < 32; i += 4) {
            float4 fv = *(const float4*)(src + i);
            Bt[(hh + i + 0) * 128 + j] = fv.x * inv;
            Bt[(hh + i + 1) * 128 + j] = fv.y * inv;
            Bt[(hh + i + 2) * 128 + j] = fv.z * inv;
            Bt[(hh + i + 3) * 128 + j] = fv.w * inv;
        }
    }

    float best_s[8];
    int   best_m[8];
    #pragma unroll
    for (int v = 0; v < 8; v++) { best_s[v] = -INFINITY; best_m[v] = INT_MAX; }

    int aj = t & 63, ack = (t >> 6) * 16;   // A-staging: center row / ch-chunk
    // preload first A sub-tile to registers
    float4 pf[4];
    {
        int mg = min(ct0 * 64 + aj, MCAP - 1);
        const float* src = cn + ((size_t)(r * MCAP + mg)) * 64 + ack;
        #pragma unroll
        for (int i = 0; i < 4; i++) pf[i] = *(const float4*)(src + i * 4);
    }
    for (int ct = ct0; ct < ctEnd; ct++) {
        __syncthreads();                    // prior At reads done (1st: covers Bt)
        #pragma unroll
        for (int i = 0; i < 4; i++) {
            At[(ack + i * 4 + 0) * 64 + aj] = pf[i].x;
            At[(ack + i * 4 + 1) * 64 + aj] = pf[i].y;
            At[(ack + i * 4 + 2) * 64 + aj] = pf[i].z;
            At[(ack + i * 4 + 3) * 64 + aj] = pf[i].w;
        }
        __syncthreads();
        if (ct + 1 < ctEnd) {               // issue next-tile loads; hide under FMA
            int mg = min((ct + 1) * 64 + aj, MCAP - 1);
            const float* src = cn + ((size_t)(r * MCAP + mg)) * 64 + ack;
            #pragma unroll
            for (int i = 0; i < 4; i++) pf[i] = *(const float4*)(src + i * 4);
        }

        float dot[4][8] = {};
        #pragma unroll 4
        for (int cc = 0; cc < 64; cc++) {
            float4 a0 = *(const float4*)(At + cc * 64 + ty * 4);
            float4 b0 = *(const float4*)(Bt + cc * 128 + tx * 4);
            float4 b1 = *(const float4*)(Bt + cc * 128 + 64 + tx * 4);
            float a[4] = {a0.x, a0.y, a0.z, a0.w};
            float b[8] = {b0.x, b0.y, b0.z, b0.w, b1.x, b1.y, b1.z, b1.w};
            #pragma unroll
            for (int u = 0; u < 4; u++) {
                #pragma unroll
                for (int v = 0; v < 8; v++)
                    dot[u][v] = fmaf(a[u], b[v], dot[u][v]);
            }
        }
        // running argmax; m ascending (ct, then u); strict > keeps smallest m
        // on exact fp32 ties (reference first-max rule)
        #pragma unroll
        for (int u = 0; u < 4; u++) {
            int mg = ct * 64 + ty * 4 + u;
            bool valid = mg < Mr;
            #pragma unroll
            for (int v = 0; v < 8; v++) {
                float s = fmaf(alpha, dot[u][v], beta);  // monotone w/ sigmoid
                if (valid && s > best_s[v]) { best_s[v] = s; best_m[v] = mg; }
            }
        }
    }

    // cross-thread (ty) reduce per key; tie -> smaller m; store partials.
    // Reuse Bt as [16][128] scratch after all compute reads are done.
    __syncthreads();
    float* rs = Bt;
    int*   rm = (int*)(Bt + 2048);
    #pragma unroll
    for (int v = 0; v < 8; v++) {
        int col = tx * 4 + (v & 3) + ((v >> 2) << 6);   // key column of this best
        rs[ty * 128 + col] = best_s[v];
        rm[ty * 128 + col] = best_m[v];
    }
    __syncthreads();
    if (t < 128) {
        float bs = rs[t]; int bm = rm[t];
        #pragma unroll
        for (int y = 1; y < 16; y++) {
            float s2 = rs[y * 128 + t]; int m2 = rm[y * 128 + t];
            if (s2 > bs || (s2 == bs && m2 < bm)) { bs = s2; bm = m2; }
        }
        size_t pb = ((size_t)((r * KT2 + kt) * CSPL + sp)) * 128;
        part_s[pb + t] = bs;
        part_m[pb + t] = bm;
    }
}

// ---------------------------------------------------------------------------
// K4b (fused): per-key split-reduce (tie -> smaller m) + sigmoid + center
// histogram + exclusive scan + ranked CSR scatter, all LDS-resident.
// One block per quadrant. Grid (4) x 1024. Replaces 3 dispatches.
// ---------------------------------------------------------------------------
__global__ __launch_bounds__(1024) void k4b_fused(
    const float* __restrict__ part_s, const int* __restrict__ part_m,
    const int* __restrict__ counts,
    float* __restrict__ win_w, int* __restrict__ cnt, int* __restrict__ basei,
    int* __restrict__ klist)
{
    __shared__ float lws[QPIX];     // 13824 B
    __shared__ int   lwm[QPIX];     // 13824 B
    __shared__ int   hist[MCAP];    // 12288 B
    __shared__ int   lbase[MCAP];   // 12288 B (becomes cursor in phase 3)
    __shared__ int   wsum[16];

    int r = blockIdx.x;
    int t = threadIdx.x;
    int K = counts[r];
    int Mr = min(K + 1, MCAP);
    int nS = (((Mr + 63) >> 6) + 1) >> 1;   // active k4a splits (2 tiles each)

    for (int i = t; i < MCAP; i += 1024) hist[i] = 0;
    __syncthreads();

    // phase 1: per-key argmax over splits, histogram winners
    for (int gk = t; gk < QPIX; gk += 1024) {
        int kt = gk >> 7, jj = gk & 127;
        size_t pb = ((size_t)((r * KT2 + kt) * CSPL)) * 128 + jj;
        float bs = -INFINITY; int bm = INT_MAX;
        for (int s = 0; s < nS; s++) {
            float s2 = part_s[pb + (size_t)s * 128];
            int   m2 = part_m[pb + (size_t)s * 128];
            if (s2 > bs || (s2 == bs && m2 < bm)) { bs = s2; bm = m2; }
        }
        if (bm < K) {   // skip phantom / empty winners
            lws[gk] = 1.0f / (1.0f + expf(-bs));
            lwm[gk] = bm;
            atomicAdd(&hist[bm], 1);
        } else {
            lwm[gk] = -1;
        }
    }
    __syncthreads();

    // phase 2: exclusive scan of hist (3 centers/thread); publish cnt/base
    {
        int i0 = t * 3;
        int v0 = hist[i0], v1 = hist[i0 + 1], v2 = hist[i0 + 2];
        int s = v0 + v1 + v2;
        int lane = t & 63, w = t >> 6;
        int incl = s;
        #pragma unroll
        for (int d = 1; d < 64; d <<= 1) {
            int n = __shfl_up(incl, d, 64);
            if (lane >= d) incl += n;
        }
        if (lane == 63) wsum[w] = incl;
        __syncthreads();
        int wbase = 0;
        for (int i = 0; i < w; i++) wbase += wsum[i];
        int excl = wbase + incl - s;
        lbase[i0]     = excl;
        lbase[i0 + 1] = excl + v0;
        lbase[i0 + 2] = excl + v0 + v1;
        cnt[r * MCAP + i0]     = v0;
        cnt[r * MCAP + i0 + 1] = v1;
        cnt[r * MCAP + i0 + 2] = v2;
        basei[r * MCAP + i0]     = excl;
        basei[r * MCAP + i0 + 1] = excl + v0;
        basei[r * MCAP + i0 + 2] = excl + v0 + v1;
    }
    __syncthreads();

    // phase 3: ranked scatter of key ids; winner weights to global
    for (int gk = t; gk < QPIX; gk += 1024) {
        int bm = lwm[gk];
        if (bm >= 0) {
            int pos = atomicAdd(&lbase[bm], 1);
            klist[r * QPIX + pos] = gk;
            win_w[r * QPIX + gk] = lws[gk];
        }
    }
}

// ---------------------------------------------------------------------------
// K4c: per-center gather-sum of winner values; non-atomic agg/denom writes.
// One wave per center. Grid (MCAP/4, 4) x 256.
// ---------------------------------------------------------------------------
__global__ __launch_bounds__(256) void k4c_agg(
    const int* __restrict__ cnt, const int* __restrict__ base,
    const int* __restrict__ klist, const float* __restrict__ win_w,
    const float* __restrict__ valp,
    float* __restrict__ agg, float* __restrict__ denom)
{
    int r = blockIdx.y;
    int m = blockIdx.x * 4 + (threadIdx.x >> 6);
    int lane = threadIdx.x & 63;
    int ci = r * MCAP + m;
    int n = cnt[ci];
    if (n == 0) return;              // agg/denom stay zero (k1 zeroed)
    int b = base[ci];
    float acc = 0.0f, ds = 0.0f;
    for (int i = 0; i < n; i++) {
        int gk = klist[r * QPIX + b + i];
        float w = win_w[r * QPIX + gk];
        acc = fmaf(w, valp[((size_t)(r * QPIX + gk)) * 64 + lane], acc);
        ds += w;
    }
    agg[((size_t)ci) * 64 + lane] = acc;
    if (lane == 0) denom[ci] = ds;
}

// ---------------------------------------------------------------------------
// K5: per-point output + projection + transposed store [1,64,1,8192].
// 32 points per block (8 passes of 4) so Wp is staged once per block.
// ---------------------------------------------------------------------------
__global__ __launch_bounds__(256) void k5_out(
    const float* __restrict__ agg, const float* __restrict__ vc,
    const float* __restrict__ denom, const int* __restrict__ slot,
    const float* __restrict__ Wp, const float* __restrict__ bp,
    float* __restrict__ out)
{
    __shared__ float WT[64 * 65];
    __shared__ float ov[4][68];
    __shared__ float res[4][64];
    int t = threadIdx.x;
    {
        int o = t >> 2, cq = (t & 3) * 16;
        #pragma unroll
        for (int i = 0; i < 16; i += 4) {
            float4 wv = *(const float4*)(Wp + o * 64 + cq + i);
            WT[(cq + i + 0) * 65 + o] = wv.x;
            WT[(cq + i + 1) * 65 + o] = wv.y;
            WT[(cq + i + 2) * 65 + o] = wv.z;
            WT[(cq + i + 3) * 65 + o] = wv.w;
        }
    }
    int p = t >> 6, c = t & 63;
    for (int pp = 0; pp < 8; pp++) {
        int n = blockIdx.x * 32 + pp * 4 + p;
        int sl = slot[n];
        float d = denom[sl] + 1.0f;
        float o_v = (agg[(size_t)sl * 64 + c] + vc[(size_t)sl * 64 + c]) / d;
        ov[p][c] = o_v;
        unsigned long long nz = __ballot(o_v != 0.0f);   // wave == point
        __syncthreads();   // ov ready (1st iter: also covers WT staging)
        float acc = bp[c];
        #pragma unroll
        for (int cc = 0; cc < 64; cc++)
            acc = fmaf(ov[p][cc], WT[cc * 65 + c], acc);
        res[p][c] = (nz != 0ull) ? acc : 0.0f;
        __syncthreads();   // res ready; ov reads done before next-pass writes
        if (t < 64) {
            float4 val = make_float4(res[0][t], res[1][t], res[2][t], res[3][t]);
            *(float4*)(out + (size_t)t * NPTS + blockIdx.x * 32 + pp * 4) = val;
        }
    }
}

// ---------------------------------------------------------------------------
extern "C" void kernel_launch(void* const* d_in, const int* in_sizes, int n_in,
                              void* d_out, int out_size, void* d_ws, size_t ws_size,
                              hipStream_t stream) {
    const float* points = (const float*)d_in[0];
    const float* x      = (const float*)d_in[1];
    const float* Wf     = (const float*)d_in[2];
    const float* bf     = (const float*)d_in[3];
    const float* Wv     = (const float*)d_in[4];
    const float* bv     = (const float*)d_in[5];
    const float* Wp     = (const float*)d_in[6];
    const float* bp     = (const float*)d_in[7];
    const float* alpha  = (const float*)d_in[8];
    const float* beta   = (const float*)d_in[9];
    float* out = (float*)d_out;

    float* ws    = (float*)d_ws;
    float* featp = ws;                        // 884736
    float* valp  = featp + 884736;            // 884736
    float* cn    = valp  + 884736;            // 786432 (4*MCAP*64)
    float* vc    = cn    + 786432;            // 786432
    float* agg   = vc    + 786432;            // 786432  (zeroed by k1)
    float* denom = agg   + 786432;            // 12288   (zeroed by k1)
    int*   cnt   = (int*)(denom + 12288);     // 12288   (fully written by k4b)
    float* invn  = (float*)(cnt + 12288);     // 13824
    float* cp    = invn  + 13824;             // 24576 (2*4*MCAP)
    float* part_s= cp    + 24576;             // 331776 (4*27*24*128)
    int*   part_m= (int*)(part_s + 331776);   // 331776
    int*   ccnt  = part_m + 331776;           // 512
    int*   counts= ccnt   + 512;              // 16
    int*   slot  = counts + 16;               // 8192
    float* win_w = (float*)(slot + 8192);     // 13824
    int*   basei = (int*)(win_w + 13824);     // 12288
    int*   klist = basei  + 12288;            // 13824
    // total ~17 MB of d_ws

    k1_linmaps<<<216, 512, 0, stream>>>(x, Wf, bf, Wv, bv, featp, valp, invn, agg);
    k2a_count  <<<128, 64, 0, stream>>>(points, ccnt);
    k2c_scatter<<<128, 64, 0, stream>>>(points, ccnt, cp, slot, counts);
    k3_gather<<<dim3(MCAP / 32, 4), 256, 0, stream>>>(featp, valp, cp, counts, cn, vc);
    k4a_sim<<<dim3(KT2, CSPL, 4), 256, 0, stream>>>(featp, invn, cn, counts,
                                                    alpha, beta, part_s, part_m);
    k4b_fused<<<4, 1024, 0, stream>>>(part_s, part_m, counts,
                                      win_w, cnt, basei, klist);
    k4c_agg<<<dim3(MCAP / 4, 4), 256, 0, stream>>>(cnt, basei, klist, win_w,
                                                   valp, agg, denom);
    k5_out<<<NPTS / 32, 256, 0, stream>>>(agg, vc, denom, slot, Wp, bp, out);
}

// Round 8
// 194.076 us; speedup vs baseline: 1.1804x; 1.0737x over previous
//
#include <hip/hip_runtime.h>
#include <math.h>
#include <float.h>
#include <limits.h>

// Problem constants
#define PIX    13824   // 64*216
#define QPIX   3456    // 32*108
#define QW     108
#define QH     32
#define NPTS   8192
#define MCAP   3072    // per-quadrant center capacity (expected ~2048, 26 sigma)
#define KT2    27      // QPIX/128 (k4a key tiles)
#define CSPL   24      // center-splits: each block 2 x 64-center tiles

// ---------------------------------------------------------------------------
// K1: feat/value linear maps + fold to [r][k][c] pixel-major + feat inv-norm.
// 512 threads: 8 waves x 8 outputs. Also zeroes agg+denom+cnt.
// ---------------------------------------------------------------------------
__global__ __launch_bounds__(512) void k1_linmaps(
    const float* __restrict__ x, const float* __restrict__ Wf, const float* __restrict__ bf,
    const float* __restrict__ Wv, const float* __restrict__ bv,
    float* __restrict__ featp, float* __restrict__ valp, float* __restrict__ invn,
    float* __restrict__ aggz)
{
    __shared__ float ssq[8][64];
    int t = threadIdx.x;

    // zero agg(786432) + denom(12288) + cnt(12288) = 811008 floats = 202752 float4
    {
        float4 z4 = make_float4(0.f, 0.f, 0.f, 0.f);
        for (int i = blockIdx.x * 512 + t; i < 202752; i += 216 * 512)
            ((float4*)aggz)[i] = z4;
    }

    int lane = t & 63;
    int q = t >> 6;                       // wave id -> o-group of 8 (wave-uniform)
    int pix = blockIdx.x * 64 + lane;     // 216*64 = 13824 exact
    int h = pix / 216;
    int w = pix - h * 216;
    int r = ((h >> 5) << 1) | (w >= QW ? 1 : 0);
    int k = (h & 31) * QW + (w >= QW ? w - QW : w);

    float xr[64];
    #pragma unroll
    for (int c = 0; c < 64; c++) xr[c] = x[c * PIX + pix];

    size_t base = ((size_t)(r * QPIX + k)) * 64 + q * 8;
    float ss = 0.0f;
    for (int i = 0; i < 8; i++) {
        int o = q * 8 + i;                // wave-uniform
        float af = bf[o], av = bv[o];
        #pragma unroll
        for (int c = 0; c < 64; c++) {
            af = fmaf(Wf[o * 64 + c], xr[c], af);
            av = fmaf(Wv[o * 64 + c], xr[c], av);
        }
        featp[base + i] = af;
        valp[base + i]  = av;
        ss += af * af;
    }
    ssq[q][lane] = ss;
    __syncthreads();
    if (q == 0) {
        float tot = 0.0f;
        #pragma unroll
        for (int i = 0; i < 8; i++) tot += ssq[i][lane];
        invn[r * QPIX + k] = 1.0f / fmaxf(sqrtf(tot), 1e-12f);
    }
}

// ---------------------------------------------------------------------------
// K2 (order-preserving compaction):
//   k2a: per-64-point-chunk quadrant counts (128 chunks)
//   k2c: per-block redundant scan of chunk counts + ranked scatter
// ---------------------------------------------------------------------------
__device__ __forceinline__ int point_quadrant(float px, float py) {
    // rh = 384/2 = 192 exact, rw = 1296/2 = 648 exact
    return ((py > 192.0f) ? 2 : 0) + ((px > 648.0f) ? 1 : 0);
}

__global__ __launch_bounds__(64) void k2a_count(
    const float* __restrict__ points, int* __restrict__ ccnt)
{
    int lane = threadIdx.x;
    int chunk = blockIdx.x;
    float2 p = ((const float2*)points)[chunk * 64 + lane];
    int q = point_quadrant(p.x, p.y);
    #pragma unroll
    for (int r = 0; r < 4; r++) {
        unsigned long long m = __ballot(q == r);
        if (lane == 0) ccnt[chunk * 4 + r] = __popcll(m);
    }
}

__global__ __launch_bounds__(64) void k2c_scatter(
    const float* __restrict__ points, const int* __restrict__ ccnt,
    float* __restrict__ cp, int* __restrict__ slot, int* __restrict__ counts)
{
    int lane = threadIdx.x;
    int chunk = blockIdx.x;

    // redundant per-block scan: prefix over chunks < my chunk, per quadrant
    int c0[4], c1[4], pre[4];
    #pragma unroll
    for (int r = 0; r < 4; r++) {
        c0[r] = ccnt[lane * 4 + r];
        c1[r] = ccnt[(lane + 64) * 4 + r];
        pre[r] = (lane < chunk ? c0[r] : 0) + (lane + 64 < chunk ? c1[r] : 0);
    }
    #pragma unroll
    for (int d = 1; d < 64; d <<= 1) {
        #pragma unroll
        for (int r = 0; r < 4; r++) pre[r] += __shfl_xor(pre[r], d, 64);
    }
    if (chunk == 0) {   // block 0 also publishes the totals
        int full[4];
        #pragma unroll
        for (int r = 0; r < 4; r++) full[r] = c0[r] + c1[r];
        #pragma unroll
        for (int d = 1; d < 64; d <<= 1) {
            #pragma unroll
            for (int r = 0; r < 4; r++) full[r] += __shfl_xor(full[r], d, 64);
        }
        if (lane == 0) {
            #pragma unroll
            for (int r = 0; r < 4; r++) counts[r] = full[r];
        }
    }

    int n = chunk * 64 + lane;
    float2 p = ((const float2*)points)[n];
    int q = point_quadrant(p.x, p.y);
    unsigned long long below = (lane == 0) ? 0ull : (~0ull >> (64 - lane));
    #pragma unroll
    for (int r = 0; r < 4; r++) {
        unsigned long long m = __ballot(q == r);
        if (q == r) {
            int pos = pre[r] + __popcll(m & below);
            ((float2*)cp)[r * MCAP + pos] = p;
            slot[n] = r * MCAP + pos;
        }
    }
}

// ---------------------------------------------------------------------------
// K3: bilinear gather (border clamp) of feat & value at compacted points;
// slot m == K_r is the phantom (0,0) padded row. 8 channel-groups x 32 points
// per block (256 threads, 8 ch/thread).
// ---------------------------------------------------------------------------
__global__ __launch_bounds__(256) void k3_gather(
    const float* __restrict__ featp, const float* __restrict__ valp,
    const float* __restrict__ cp, const int* __restrict__ counts,
    float* __restrict__ cn, float* __restrict__ vc)
{
    __shared__ float ssq[32][9];
    int r = blockIdx.y;
    int t = threadIdx.x;
    int g = t & 7, p = t >> 3;          // g: channel group (8ch), p: point in tile
    int m = blockIdx.x * 32 + p;
    int K = counts[r];
    int Mr = min(K + 1, MCAP);
    bool active = m < Mr;

    float px = 0.0f, py = 0.0f;
    if (m < K) { float2 pt = ((const float2*)cp)[r * MCAP + m]; px = pt.x; py = pt.y; }

    // mirror reference op order: grid = p/(S-1)*2-1 ; g = (grid+1)*(D/2)-0.5
    float gx = (px / 1295.0f * 2.0f - 1.0f + 1.0f) * 54.0f - 0.5f;
    float gy = (py / 383.0f  * 2.0f - 1.0f + 1.0f) * 16.0f - 0.5f;
    float x0 = floorf(gx), y0 = floorf(gy);
    float wx = gx - x0, wy = gy - y0;
    int x0i = (int)fminf(fmaxf(x0,         0.0f), 107.0f);
    int x1i = (int)fminf(fmaxf(x0 + 1.0f,  0.0f), 107.0f);
    int y0i = (int)fminf(fmaxf(y0,         0.0f), 31.0f);
    int y1i = (int)fminf(fmaxf(y0 + 1.0f,  0.0f), 31.0f);
    float w00 = (1.0f - wx) * (1.0f - wy);
    float w01 = wx * (1.0f - wy);
    float w10 = (1.0f - wx) * wy;
    float w11 = wx * wy;

    int c0 = g * 8;
    size_t b00 = ((size_t)(r * QPIX + y0i * QW + x0i)) * 64 + c0;
    size_t b01 = ((size_t)(r * QPIX + y0i * QW + x1i)) * 64 + c0;
    size_t b10 = ((size_t)(r * QPIX + y1i * QW + x0i)) * 64 + c0;
    size_t b11 = ((size_t)(r * QPIX + y1i * QW + x1i)) * 64 + c0;
    size_t ob  = ((size_t)(r * MCAP + m)) * 64 + c0;

    float fr[8];
    float ss = 0.0f;
    #pragma unroll
    for (int c = 0; c < 8; c += 4) {
        float4 a  = *(const float4*)(featp + b00 + c);
        float4 b_ = *(const float4*)(featp + b01 + c);
        float4 gg = *(const float4*)(featp + b10 + c);
        float4 d  = *(const float4*)(featp + b11 + c);
        float e0 = a.x * w00 + b_.x * w01 + gg.x * w10 + d.x * w11;
        float e1 = a.y * w00 + b_.y * w01 + gg.y * w10 + d.y * w11;
        float e2 = a.z * w00 + b_.z * w01 + gg.z * w10 + d.z * w11;
        float e3 = a.w * w00 + b_.w * w01 + gg.w * w10 + d.w * w11;
        fr[c] = e0; fr[c+1] = e1; fr[c+2] = e2; fr[c+3] = e3;
        ss += e0*e0; ss += e1*e1; ss += e2*e2; ss += e3*e3;
    }
    ssq[p][g] = ss;
    __syncthreads();
    float tot = 0.0f;
    #pragma unroll
    for (int i = 0; i < 8; i++) tot += ssq[p][i];
    float inv = 1.0f / fmaxf(sqrtf(tot), 1e-12f);

    if (active) {
        #pragma unroll
        for (int c = 0; c < 8; c += 4) {
            *(float4*)(cn + ob + c) =
                make_float4(fr[c]*inv, fr[c+1]*inv, fr[c+2]*inv, fr[c+3]*inv);
        }
        #pragma unroll
        for (int c = 0; c < 8; c += 4) {
            float4 a  = *(const float4*)(valp + b00 + c);
            float4 b_ = *(const float4*)(valp + b01 + c);
            float4 gg = *(const float4*)(valp + b10 + c);
            float4 d  = *(const float4*)(valp + b11 + c);
            float4 o;
            o.x = a.x * w00 + b_.x * w01 + gg.x * w10 + d.x * w11;
            o.y = a.y * w00 + b_.y * w01 + gg.y * w10 + d.y * w11;
            o.z = a.z * w00 + b_.z * w01 + gg.z * w10 + d.z * w11;
            o.w = a.w * w00 + b_.w * w01 + gg.w * w10 + d.w * w11;
            *(float4*)(vc + ob + c) = o;
        }
    }
}

// ---------------------------------------------------------------------------
// K4a v7: 128 keys x 64 centers/tile, 2 tiles/block, frag 4x8, LDS 48 KiB ->
// 3 blocks/CU, register-prefetched A staging. At ~91% of its ds_read_b128
// throughput floor (53.5 us) - structurally converged at this frag shape.
// ---------------------------------------------------------------------------
__global__ __launch_bounds__(256) void k4a_sim(
    const float* __restrict__ featp, const float* __restrict__ invn,
    const float* __restrict__ cn, const int* __restrict__ counts,
    const float* __restrict__ alpha_p, const float* __restrict__ beta_p,
    float* __restrict__ part_s, int* __restrict__ part_m)
{
    __shared__ float Bt[64 * 128];   // [ch][key]     32 KiB
    __shared__ float At[64 * 64];    // [ch][center]  16 KiB

    int r  = blockIdx.z;
    int kt = blockIdx.x;
    int sp = blockIdx.y;
    int k0 = kt * 128;
    int t  = threadIdx.x;
    int tx = t & 15, ty = t >> 4;    // tx -> 8 keys (2 groups of 4), ty -> 4 centers
    int K  = counts[r];
    int Mr = min(K + 1, MCAP);
    int ntiles = (Mr + 63) >> 6;
    int ct0 = sp * 2;
    if (ct0 >= ntiles) return;       // k4b1 only reads partials for sp < ceil(ntiles/2)
    int ctEnd = min(ct0 + 2, ntiles);
    float alpha = alpha_p[0], beta = beta_p[0];

    // stage B tile: 128 keys x 64 ch, normalized, channel-major
    {
        int j = t >> 1, hh = (t & 1) * 32;
        float inv = invn[r * QPIX + k0 + j];
        const float* src = featp + ((size_t)(r * QPIX + k0 + j)) * 64 + hh;
        #pragma unroll
        for (int i = 0; i < 32; i += 4) {
            float4 fv = *(const float4*)(src + i);
            Bt[(hh + i + 0) * 128 + j] = fv.x * inv;
            Bt[(hh + i + 1) * 128 + j] = fv.y * inv;
            Bt[(hh + i + 2) * 128 + j] = fv.z * inv;
            Bt[(hh + i + 3) * 128 + j] = fv.w * inv;
        }
    }

    float best_s[8];
    int   best_m[8];
    #pragma unroll
    for (int v = 0; v < 8; v++) { best_s[v] = -INFINITY; best_m[v] = INT_MAX; }

    int aj = t & 63, ack = (t >> 6) * 16;   // A-staging: center row / ch-chunk
    // preload first A sub-tile to registers
    float4 pf[4];
    {
        int mg = min(ct0 * 64 + aj, MCAP - 1);
        const float* src = cn + ((size_t)(r * MCAP + mg)) * 64 + ack;
        #pragma unroll
        for (int i = 0; i < 4; i++) pf[i] = *(const float4*)(src + i * 4);
    }
    for (int ct = ct0; ct < ctEnd; ct++) {
        __syncthreads();                    // prior At reads done (1st: covers Bt)
        #pragma unroll
        for (int i = 0; i < 4; i++) {
            At[(ack + i * 4 + 0) * 64 + aj] = pf[i].x;
            At[(ack + i * 4 + 1) * 64 + aj] = pf[i].y;
            At[(ack + i * 4 + 2) * 64 + aj] = pf[i].z;
            At[(ack + i * 4 + 3) * 64 + aj] = pf[i].w;
        }
        __syncthreads();
        if (ct + 1 < ctEnd) {               // issue next-tile loads; hide under FMA
            int mg = min((ct + 1) * 64 + aj, MCAP - 1);
            const float* src = cn + ((size_t)(r * MCAP + mg)) * 64 + ack;
            #pragma unroll
            for (int i = 0; i < 4; i++) pf[i] = *(const float4*)(src + i * 4);
        }

        float dot[4][8] = {};
        #pragma unroll 4
        for (int cc = 0; cc < 64; cc++) {
            float4 a0 = *(const float4*)(At + cc * 64 + ty * 4);
            float4 b0 = *(const float4*)(Bt + cc * 128 + tx * 4);
            float4 b1 = *(const float4*)(Bt + cc * 128 + 64 + tx * 4);
            float a[4] = {a0.x, a0.y, a0.z, a0.w};
            float b[8] = {b0.x, b0.y, b0.z, b0.w, b1.x, b1.y, b1.z, b1.w};
            #pragma unroll
            for (int u = 0; u < 4; u++) {
                #pragma unroll
                for (int v = 0; v < 8; v++)
                    dot[u][v] = fmaf(a[u], b[v], dot[u][v]);
            }
        }
        // running argmax; m ascending (ct, then u); strict > keeps smallest m
        // on exact fp32 ties (reference first-max rule)
        #pragma unroll
        for (int u = 0; u < 4; u++) {
            int mg = ct * 64 + ty * 4 + u;
            bool valid = mg < Mr;
            #pragma unroll
            for (int v = 0; v < 8; v++) {
                float s = fmaf(alpha, dot[u][v], beta);  // monotone w/ sigmoid
                if (valid && s > best_s[v]) { best_s[v] = s; best_m[v] = mg; }
            }
        }
    }

    // cross-thread (ty) reduce per key; tie -> smaller m; store partials.
    // Reuse Bt as [16][128] scratch after all compute reads are done.
    __syncthreads();
    float* rs = Bt;
    int*   rm = (int*)(Bt + 2048);
    #pragma unroll
    for (int v = 0; v < 8; v++) {
        int col = tx * 4 + (v & 3) + ((v >> 2) << 6);   // key column of this best
        rs[ty * 128 + col] = best_s[v];
        rm[ty * 128 + col] = best_m[v];
    }
    __syncthreads();
    if (t < 128) {
        float bs = rs[t]; int bm = rm[t];
        #pragma unroll
        for (int y = 1; y < 16; y++) {
            float s2 = rs[y * 128 + t]; int m2 = rm[y * 128 + t];
            if (s2 > bs || (s2 == bs && m2 < bm)) { bs = s2; bm = m2; }
        }
        size_t pb = ((size_t)((r * KT2 + kt) * CSPL + sp)) * 128;
        part_s[pb + t] = bs;
        part_m[pb + t] = bm;
    }
}

// ---------------------------------------------------------------------------
// K4b1: reduce split partials per key (tie -> smaller m), sigmoid, and build
// the center histogram (int atomics only). Grid (KT2, 4) x 128 = 108 blocks:
// the latency-bound partial reads need this parallelism (4-block fusion of
// this phase was the R7 regression).
// ---------------------------------------------------------------------------
__global__ __launch_bounds__(128) void k4b1_argmax(
    const float* __restrict__ part_s, const int* __restrict__ part_m,
    const int* __restrict__ counts,
    int* __restrict__ win_m, float* __restrict__ win_w, int* __restrict__ cnt)
{
    int r  = blockIdx.y;
    int kt = blockIdx.x;
    int t  = threadIdx.x;
    int gk = kt * 128 + t;
    int K  = counts[r];
    int Mr = min(K + 1, MCAP);
    int nS = (((Mr + 63) >> 6) + 1) >> 1;   // active k4a splits (2 tiles each)

    size_t pb = ((size_t)((r * KT2 + kt) * CSPL)) * 128;
    float bs = -INFINITY; int bm = INT_MAX;
    for (int s = 0; s < nS; s++) {
        float s2 = part_s[pb + (size_t)s * 128 + t];
        int   m2 = part_m[pb + (size_t)s * 128 + t];
        if (s2 > bs || (s2 == bs && m2 < bm)) { bs = s2; bm = m2; }
    }
    if (bm < K) {   // skip phantom / empty winners
        win_m[r * QPIX + gk] = bm;
        win_w[r * QPIX + gk] = 1.0f / (1.0f + expf(-bs));
        atomicAdd(&cnt[r * MCAP + bm], 1);
    } else {
        win_m[r * QPIX + gk] = -1;
    }
}

// ---------------------------------------------------------------------------
// K4bs: exclusive scan of center histogram + ranked CSR scatter of key ids.
// Light phase only (12KB cnt + 55KB win_m reads). Grid (4) x 1024.
// ---------------------------------------------------------------------------
__global__ __launch_bounds__(1024) void k4bs_scan_scatter(
    const int* __restrict__ cnt, const int* __restrict__ win_m,
    int* __restrict__ basei, int* __restrict__ klist)
{
    __shared__ int lbase[MCAP];     // scan result, then cursor
    __shared__ int wsum[16];
    int r = blockIdx.x;
    int t = threadIdx.x;

    int i0 = t * 3;                 // 3 centers/thread (3072 = 1024*3)
    int ci = r * MCAP + i0;
    int v0 = cnt[ci], v1 = cnt[ci + 1], v2 = cnt[ci + 2];
    int s = v0 + v1 + v2;
    int lane = t & 63, w = t >> 6;
    int incl = s;
    #pragma unroll
    for (int d = 1; d < 64; d <<= 1) {
        int n = __shfl_up(incl, d, 64);
        if (lane >= d) incl += n;
    }
    if (lane == 63) wsum[w] = incl;
    __syncthreads();
    int wbase = 0;
    for (int i = 0; i < w; i++) wbase += wsum[i];
    int excl = wbase + incl - s;
    lbase[i0]     = excl;
    lbase[i0 + 1] = excl + v0;
    lbase[i0 + 2] = excl + v0 + v1;
    basei[ci]     = excl;
    basei[ci + 1] = excl + v0;
    basei[ci + 2] = excl + v0 + v1;
    __syncthreads();

    for (int gk = t; gk < QPIX; gk += 1024) {
        int bm = win_m[r * QPIX + gk];
        if (bm >= 0) {
            int pos = atomicAdd(&lbase[bm], 1);
            klist[r * QPIX + pos] = gk;
        }
    }
}

// ---------------------------------------------------------------------------
// K4c: per-center gather-sum of winner values; non-atomic agg/denom writes.
// One wave per center. Grid (MCAP/4, 4) x 256.
// ---------------------------------------------------------------------------
__global__ __launch_bounds__(256) void k4c_agg(
    const int* __restrict__ cnt, const int* __restrict__ base,
    const int* __restrict__ klist, const float* __restrict__ win_w,
    const float* __restrict__ valp,
    float* __restrict__ agg, float* __restrict__ denom)
{
    int r = blockIdx.y;
    int m = blockIdx.x * 4 + (threadIdx.x >> 6);
    int lane = threadIdx.x & 63;
    int ci = r * MCAP + m;
    int n = cnt[ci];
    if (n == 0) return;              // agg/denom stay zero (k1 zeroed)
    int b = base[ci];
    float acc = 0.0f, ds = 0.0f;
    for (int i = 0; i < n; i++) {
        int gk = klist[r * QPIX + b + i];
        float w = win_w[r * QPIX + gk];
        acc = fmaf(w, valp[((size_t)(r * QPIX + gk)) * 64 + lane], acc);
        ds += w;
    }
    agg[((size_t)ci) * 64 + lane] = acc;
    if (lane == 0) denom[ci] = ds;
}

// ---------------------------------------------------------------------------
// K5: per-point output + projection + transposed store [1,64,1,8192].
// 32 points per block; Wp row c held in 16 float4 VGPRs per thread (one-time
// L2 gather) and ov read as broadcast ds_read_b128: 16 LDS reads per pass
// instead of 128 - removes k5's LDS-pipe bottleneck. Same fmaf order.
// ---------------------------------------------------------------------------
__global__ __launch_bounds__(256) void k5_out(
    const float* __restrict__ agg, const float* __restrict__ vc,
    const float* __restrict__ denom, const int* __restrict__ slot,
    const float* __restrict__ Wp, const float* __restrict__ bp,
    float* __restrict__ out)
{
    __shared__ float ov[4][68];
    __shared__ float res[4][64];
    int t = threadIdx.x;
    int p = t >> 6, c = t & 63;

    float4 wr[16];
    #pragma unroll
    for (int i = 0; i < 16; i++) wr[i] = *(const float4*)(Wp + c * 64 + i * 4);
    float bc = bp[c];

    for (int pp = 0; pp < 8; pp++) {
        int n = blockIdx.x * 32 + pp * 4 + p;
        int sl = slot[n];
        float d = denom[sl] + 1.0f;
        float o_v = (agg[(size_t)sl * 64 + c] + vc[(size_t)sl * 64 + c]) / d;
        ov[p][c] = o_v;
        unsigned long long nz = __ballot(o_v != 0.0f);   // wave == point
        __syncthreads();   // ov ready
        float acc = bc;
        #pragma unroll
        for (int i = 0; i < 16; i++) {
            float4 o4 = *(const float4*)(&ov[p][i * 4]);   // broadcast b128
            acc = fmaf(o4.x, wr[i].x, acc);
            acc = fmaf(o4.y, wr[i].y, acc);
            acc = fmaf(o4.z, wr[i].z, acc);
            acc = fmaf(o4.w, wr[i].w, acc);
        }
        res[p][c] = (nz != 0ull) ? acc : 0.0f;
        __syncthreads();   // res ready; ov reads done before next-pass writes
        if (t < 64) {
            float4 val = make_float4(res[0][t], res[1][t], res[2][t], res[3][t]);
            *(float4*)(out + (size_t)t * NPTS + blockIdx.x * 32 + pp * 4) = val;
        }
    }
}

// ---------------------------------------------------------------------------
extern "C" void kernel_launch(void* const* d_in, const int* in_sizes, int n_in,
                              void* d_out, int out_size, void* d_ws, size_t ws_size,
                              hipStream_t stream) {
    const float* points = (const float*)d_in[0];
    const float* x      = (const float*)d_in[1];
    const float* Wf     = (const float*)d_in[2];
    const float* bf     = (const float*)d_in[3];
    const float* Wv     = (const float*)d_in[4];
    const float* bv     = (const float*)d_in[5];
    const float* Wp     = (const float*)d_in[6];
    const float* bp     = (const float*)d_in[7];
    const float* alpha  = (const float*)d_in[8];
    const float* beta   = (const float*)d_in[9];
    float* out = (float*)d_out;

    float* ws    = (float*)d_ws;
    float* featp = ws;                        // 884736
    float* valp  = featp + 884736;            // 884736
    float* cn    = valp  + 884736;            // 786432 (4*MCAP*64)
    float* vc    = cn    + 786432;            // 786432
    float* agg   = vc    + 786432;            // 786432  (zeroed by k1)
    float* denom = agg   + 786432;            // 12288   (zeroed by k1)
    int*   cnt   = (int*)(denom + 12288);     // 12288   (zeroed by k1)
    float* invn  = (float*)(cnt + 12288);     // 13824
    float* cp    = invn  + 13824;             // 24576 (2*4*MCAP)
    float* part_s= cp    + 24576;             // 331776 (4*27*24*128)
    int*   part_m= (int*)(part_s + 331776);   // 331776
    int*   ccnt  = part_m + 331776;           // 512
    int*   counts= ccnt   + 512;              // 16
    int*   slot  = counts + 16;               // 8192
    int*   win_m = slot   + 8192;             // 13824
    float* win_w = (float*)(win_m + 13824);   // 13824
    int*   basei = (int*)(win_w + 13824);     // 12288
    int*   klist = basei  + 12288;            // 13824
    // total ~17 MB of d_ws

    k1_linmaps<<<216, 512, 0, stream>>>(x, Wf, bf, Wv, bv, featp, valp, invn, agg);
    k2a_count  <<<128, 64, 0, stream>>>(points, ccnt);
    k2c_scatter<<<128, 64, 0, stream>>>(points, ccnt, cp, slot, counts);
    k3_gather<<<dim3(MCAP / 32, 4), 256, 0, stream>>>(featp, valp, cp, counts, cn, vc);
    k4a_sim<<<dim3(KT2, CSPL, 4), 256, 0, stream>>>(featp, invn, cn, counts,
                                                    alpha, beta, part_s, part_m);
    k4b1_argmax<<<dim3(KT2, 4), 128, 0, stream>>>(part_s, part_m, counts,
                                                  win_m, win_w, cnt);
    k4bs_scan_scatter<<<4, 1024, 0, stream>>>(cnt, win_m, basei, klist);
    k4c_agg<<<dim3(MCAP / 4, 4), 256, 0, stream>>>(cnt, basei, klist, win_w,
                                                   valp, agg, denom);
    k5_out<<<NPTS / 32, 256, 0, stream>>>(agg, vc, denom, slot, Wp, bp, out);
}